// Round 4
// baseline (1241.389 us; speedup 1.0000x reference)
//
#include <hip/hip_runtime.h>
#include <hip/hip_bf16.h>
#include <cmath>

// WRGCN: 2-layer weighted relational GCN.
// N=100000, E=3200000, R=8, F_IN=128, DIMS=64, C=40.
// dst-CSR via bucketed two-phase fill; 8-wide-pipelined gathers; all GEMMs
// (incl. root) on bf16 MFMA.

#define RELS 8
#define BKT_NODES 128
#define BKT_CAP 8192

typedef __attribute__((ext_vector_type(8))) short bf16x8;
typedef __attribute__((ext_vector_type(4))) float f32x4;

static __device__ __forceinline__ ushort f2bf(float f) {
    __hip_bfloat16 b = __float2bfloat16(f);
    return *reinterpret_cast<ushort*>(&b);
}
static __device__ __forceinline__ float bf2f(ushort u) {
    return __uint_as_float(((unsigned int)u) << 16);
}

// ---------------------------------------------------------------------------
// Casts / weight prep
// ---------------------------------------------------------------------------
__global__ __launch_bounds__(256) void cast_f32_bf16x4(
    const float* __restrict__ in, ushort* __restrict__ out, int n4)
{
    int i = blockIdx.x * 256 + threadIdx.x;
    if (i >= n4) return;
    float4 v = ((const float4*)in)[i];
    ushort4 o;
    o.x = f2bf(v.x); o.y = f2bf(v.y); o.z = f2bf(v.z); o.w = f2bf(v.w);
    ((ushort4*)out)[i] = o;
}

__global__ __launch_bounds__(256) void cast_relu_bf16x4(
    const float* __restrict__ in, ushort* __restrict__ out, int n4)
{
    int i = blockIdx.x * 256 + threadIdx.x;
    if (i >= n4) return;
    float4 v = ((const float4*)in)[i];
    ushort4 o;
    o.x = f2bf(fmaxf(v.x, 0.f)); o.y = f2bf(fmaxf(v.y, 0.f));
    o.z = f2bf(fmaxf(v.z, 0.f)); o.w = f2bf(fmaxf(v.w, 0.f));
    ((ushort4*)out)[i] = o;
}

// w1t[r][c][k]: r in [0,9): r<8 from W1_rel [R][128][64]; r==8 from W1_root.
__global__ __launch_bounds__(256) void conv_w1(
    const float* __restrict__ Wrel, const float* __restrict__ Wroot,
    ushort* __restrict__ wt)
{
    int i = blockIdx.x * 256 + threadIdx.x;
    if (i >= 9 * 64 * 128) return;
    int r = i >> 13, c = (i >> 7) & 63, k = i & 127;
    float v = (r < 8) ? Wrel[((size_t)r * 128 + k) * 64 + c]
                      : Wroot[(size_t)k * 64 + c];
    wt[i] = f2bf(v);
}

// w2t[r][c][k]: r in [0,9), c in [0,48) (pad 40..47 = 0), k in [0,64).
__global__ __launch_bounds__(256) void conv_w2(
    const float* __restrict__ Wrel, const float* __restrict__ Wroot,
    ushort* __restrict__ wt)
{
    int i = blockIdx.x * 256 + threadIdx.x;
    if (i >= 9 * 48 * 64) return;
    int r = i / (48 * 64), rem = i - r * (48 * 64);
    int c = rem >> 6, k = rem & 63;
    float v = 0.f;
    if (c < 40)
        v = (r < 8) ? Wrel[((size_t)r * 64 + k) * 40 + c]
                    : Wroot[(size_t)k * 40 + c];
    wt[i] = f2bf(v);
}

// ---------------------------------------------------------------------------
// Layer-1 GEMMs (MFMA bf16), blockIdx.y in [0,9):
//   y<8 : h[y][n][0:64] = xb[n][0:128] @ W1_rel[y]      (bf16 out)
//   y==8: agg1[n][0:64] = xb[n][0:128] @ W1_root + b1   (f32 out)
// ---------------------------------------------------------------------------
__global__ __launch_bounds__(256) void gemm1_mfma(
    const ushort* __restrict__ xb, const ushort* __restrict__ w1t,
    ushort* __restrict__ hout, float* __restrict__ agg1,
    const float* __restrict__ b1, int nN)
{
    __shared__ ushort xs[64 * 128];
    __shared__ ushort wt[64 * 128];
    const int y    = blockIdx.y;
    const int tid  = threadIdx.x;
    const int n0   = blockIdx.x * 64;
    const int nmax = nN - n0;
    const bool isroot = (y == 8);
    ushort* out = hout + (size_t)y * nN * 64;
    const ushort* wsrc = w1t + (size_t)y * 64 * 128;

    for (int i = tid; i < 1024; i += 256) {
        int row = i >> 4, ch = i & 15;
        uint4 v = make_uint4(0u, 0u, 0u, 0u);
        if (row < nmax)
            v = *(const uint4*)(xb + (size_t)(n0 + row) * 128 + ch * 8);
        int off = (row * 256 + ch * 16) ^ ((row & 7) << 4);
        *(uint4*)((char*)xs + off) = v;
    }
    for (int i = tid; i < 1024; i += 256) {
        int row = i >> 4, ch = i & 15;
        uint4 v = *(const uint4*)(wsrc + (size_t)row * 128 + ch * 8);
        int off = (row * 256 + ch * 16) ^ ((row & 7) << 4);
        *(uint4*)((char*)wt + off) = v;
    }
    __syncthreads();

    const int wv   = tid >> 6;
    const int lane = tid & 63;
    const int lr   = wv * 16 + (lane & 15);
    const int kgb  = (lane >> 4) * 8;

    f32x4 acc[4] = {{0.f,0.f,0.f,0.f},{0.f,0.f,0.f,0.f},
                    {0.f,0.f,0.f,0.f},{0.f,0.f,0.f,0.f}};

    #pragma unroll
    for (int ks = 0; ks < 4; ++ks) {
        int kb = (ks * 32 + kgb) * 2;
        int aoff = (lr * 256 + kb) ^ ((lr & 7) << 4);
        bf16x8 a = *(const bf16x8*)((const char*)xs + aoff);
        #pragma unroll
        for (int ct = 0; ct < 4; ++ct) {
            int col = ct * 16 + (lane & 15);
            int boff = (col * 256 + kb) ^ ((col & 7) << 4);
            bf16x8 b = *(const bf16x8*)((const char*)wt + boff);
            acc[ct] = __builtin_amdgcn_mfma_f32_16x16x32_bf16(a, b, acc[ct], 0, 0, 0);
        }
    }

    #pragma unroll
    for (int ct = 0; ct < 4; ++ct) {
        int col = ct * 16 + (lane & 15);
        #pragma unroll
        for (int reg = 0; reg < 4; ++reg) {
            int row = wv * 16 + (lane >> 4) * 4 + reg;
            if (row < nmax) {
                if (isroot)
                    agg1[(size_t)(n0 + row) * 64 + col] = acc[ct][reg] + b1[col];
                else
                    out[(size_t)(n0 + row) * 64 + col] = f2bf(acc[ct][reg]);
            }
        }
    }
}

// ---------------------------------------------------------------------------
// Layer-2 GEMMs (MFMA bf16), blockIdx.y in [0,9):
//   y<8 : h2[y][n][0:40] = y1b[n][0:64] @ W2_rel[y]     (bf16 out)
//   y==8: agg2[n][0:40] = y1b[n][0:64] @ W2_root + b2   (f32 out)
// ---------------------------------------------------------------------------
__global__ __launch_bounds__(256) void gemm2_mfma(
    const ushort* __restrict__ y1b, const ushort* __restrict__ w2t,
    ushort* __restrict__ hout, float* __restrict__ agg2,
    const float* __restrict__ b2, int nN)
{
    __shared__ ushort ys[64 * 64];
    __shared__ ushort wt[48 * 64];
    const int y    = blockIdx.y;
    const int tid  = threadIdx.x;
    const int n0   = blockIdx.x * 64;
    const int nmax = nN - n0;
    const bool isroot = (y == 8);
    ushort* out = hout + (size_t)y * nN * 40;
    const ushort* wsrc = w2t + (size_t)y * 48 * 64;

    for (int i = tid; i < 512; i += 256) {
        int row = i >> 3, ch = i & 7;
        uint4 v = make_uint4(0u, 0u, 0u, 0u);
        if (row < nmax)
            v = *(const uint4*)(y1b + (size_t)(n0 + row) * 64 + ch * 8);
        int off = (row * 128 + ch * 16) ^ ((row & 7) << 4);
        *(uint4*)((char*)ys + off) = v;
    }
    for (int i = tid; i < 384; i += 256) {
        int row = i >> 3, ch = i & 7;
        uint4 v = *(const uint4*)(wsrc + (size_t)row * 64 + ch * 8);
        int off = (row * 128 + ch * 16) ^ ((row & 7) << 4);
        *(uint4*)((char*)wt + off) = v;
    }
    __syncthreads();

    const int wv   = tid >> 6;
    const int lane = tid & 63;
    const int lr   = wv * 16 + (lane & 15);
    const int kgb  = (lane >> 4) * 8;

    f32x4 acc[3] = {{0.f,0.f,0.f,0.f},{0.f,0.f,0.f,0.f},{0.f,0.f,0.f,0.f}};

    #pragma unroll
    for (int ks = 0; ks < 2; ++ks) {
        int kb = (ks * 32 + kgb) * 2;
        int aoff = (lr * 128 + kb) ^ ((lr & 7) << 4);
        bf16x8 a = *(const bf16x8*)((const char*)ys + aoff);
        #pragma unroll
        for (int ct = 0; ct < 3; ++ct) {
            int col = ct * 16 + (lane & 15);
            int boff = (col * 128 + kb) ^ ((col & 7) << 4);
            bf16x8 b = *(const bf16x8*)((const char*)wt + boff);
            acc[ct] = __builtin_amdgcn_mfma_f32_16x16x32_bf16(a, b, acc[ct], 0, 0, 0);
        }
    }

    #pragma unroll
    for (int ct = 0; ct < 3; ++ct) {
        int col = ct * 16 + (lane & 15);
        if (col < 40) {
            #pragma unroll
            for (int reg = 0; reg < 4; ++reg) {
                int row = wv * 16 + (lane >> 4) * 4 + reg;
                if (row < nmax) {
                    if (isroot)
                        agg2[(size_t)(n0 + row) * 40 + col] = acc[ct][reg] + b2[col];
                    else
                        out[(size_t)(n0 + row) * 40 + col] = f2bf(acc[ct][reg]);
                }
            }
        }
    }
}

// ---------------------------------------------------------------------------
// CSR build: histogram -> scan -> bucketed two-phase fill
// payload pk: bits 0..19 src, 20..22 color, 23..29 local-dst (dst & 127)
// ---------------------------------------------------------------------------
__global__ __launch_bounds__(256) void hist_dst(
    const int* __restrict__ dst, int* __restrict__ counts, int nE)
{
    int e = blockIdx.x * 256 + threadIdx.x;
    if (e < nE) atomicAdd(&counts[dst[e]], 1);
}

__global__ __launch_bounds__(256) void scan_partial(
    const int* __restrict__ counts, int* __restrict__ bsum, int nN)
{
    __shared__ int s[256];
    int t = threadIdx.x;
    int i = blockIdx.x * 256 + t;
    int v = (i < nN) ? counts[i] : 0;
    s[t] = v; __syncthreads();
    for (int o = 1; o < 256; o <<= 1) {
        int u = (t >= o) ? s[t - o] : 0;
        __syncthreads(); s[t] += u; __syncthreads();
    }
    if (t == 255) bsum[blockIdx.x] = s[255];
}

__global__ __launch_bounds__(512) void scan_base(
    const int* __restrict__ bsum, int* __restrict__ bbase, int nb,
    int* __restrict__ row_off, int nN)
{
    __shared__ int s[512];
    int t = threadIdx.x;
    int v = (t < nb) ? bsum[t] : 0;
    s[t] = v; __syncthreads();
    for (int o = 1; o < 512; o <<= 1) {
        int u = (t >= o) ? s[t - o] : 0;
        __syncthreads(); s[t] += u; __syncthreads();
    }
    if (t < nb) bbase[t] = s[t] - v;
    if (t == nb - 1) row_off[nN] = s[t];
}

__global__ __launch_bounds__(256) void scan_final(
    const int* __restrict__ counts, const int* __restrict__ bbase,
    int* __restrict__ row_off, int* __restrict__ cursor, int nN)
{
    __shared__ int s[256];
    int t = threadIdx.x;
    int i = blockIdx.x * 256 + t;
    int v = (i < nN) ? counts[i] : 0;
    s[t] = v; __syncthreads();
    for (int o = 1; o < 256; o <<= 1) {
        int u = (t >= o) ? s[t - o] : 0;
        __syncthreads(); s[t] += u; __syncthreads();
    }
    if (i < nN) {
        int off = bbase[blockIdx.x] + s[t] - v;
        row_off[i] = off;
        cursor[i]  = off;
    }
}

__global__ __launch_bounds__(256) void init_bcur(
    const int* __restrict__ row_off, int* __restrict__ bcur, int nB, int nN)
{
    int i = blockIdx.x * 256 + threadIdx.x;
    if (i < nB) bcur[i] = row_off[min(i * BKT_NODES, nN)];
}

// Phase A: append into bucket-contiguous CSR region (write frontier = nB lines)
__global__ __launch_bounds__(256) void bucket_fill(
    const int* __restrict__ src, const int* __restrict__ dst,
    const float* __restrict__ ew, const int* __restrict__ ec,
    int* __restrict__ bcur, uint2* __restrict__ epackA, int nE)
{
    int e = blockIdx.x * 256 + threadIdx.x;
    if (e >= nE) return;
    int d = dst[e];
    int p = atomicAdd(&bcur[d >> 7], 1);
    epackA[p] = make_uint2((unsigned int)src[e] | ((unsigned int)ec[e] << 20)
                           | ((unsigned int)(d & 127) << 23),
                           __float_as_uint(ew[e]));
}

// Phase B: per-bucket LDS reorder into exact per-node slots, sequential out.
__global__ __launch_bounds__(256) void reorder_bucket(
    const uint2* __restrict__ epackA, const int* __restrict__ row_off,
    int* __restrict__ gcur, uint2* __restrict__ epack, int nN)
{
    __shared__ uint2 stag[BKT_CAP];
    __shared__ int lcur[BKT_NODES];
    const int b    = blockIdx.x;
    const int n0   = b * BKT_NODES;
    const int nend = min(n0 + BKT_NODES, nN);
    const int seg0 = row_off[n0];
    const int seg1 = row_off[nend];
    const int ne   = seg1 - seg0;
    const int t    = threadIdx.x;
    if (t < BKT_NODES) {
        int idx = n0 + t;
        lcur[t] = (idx < nN) ? (row_off[idx] - seg0) : ne;
    }
    __syncthreads();
    if (ne <= BKT_CAP) {
        for (int e = t; e < ne; e += 256) {
            uint2 pw = epackA[seg0 + e];
            int ld = (pw.x >> 23) & 127;
            int p = atomicAdd(&lcur[ld], 1);
            stag[p] = pw;
        }
        __syncthreads();
        for (int e = t; e < ne; e += 256)
            epack[seg0 + e] = stag[e];
    } else {
        // adversarial-degree fallback: global per-node cursors
        for (int e = t; e < ne; e += 256) {
            uint2 pw = epackA[seg0 + e];
            int d = n0 + ((pw.x >> 23) & 127);
            int p = atomicAdd(&gcur[d], 1);
            epack[p] = pw;
        }
    }
}

// ws-too-small fallback: direct scatter fill (round-3 path)
__global__ __launch_bounds__(256) void fill_csr(
    const int* __restrict__ src, const int* __restrict__ dst,
    const float* __restrict__ ew, const int* __restrict__ ec,
    int* __restrict__ cursor, uint2* __restrict__ epack, int nE)
{
    int e = blockIdx.x * 256 + threadIdx.x;
    if (e >= nE) return;
    int p = atomicAdd(&cursor[dst[e]], 1);
    epack[p] = make_uint2((unsigned int)src[e] | ((unsigned int)ec[e] << 20),
                          __float_as_uint(ew[e]));
}

// ---------------------------------------------------------------------------
// Gather aggregation, DIMS=64: one wave per dst node, lane = dim.
// 8-wide software pipeline: 8 independent loads in flight per wave.
// ---------------------------------------------------------------------------
__global__ __launch_bounds__(256) void gather_d64(
    const ushort* __restrict__ h, const int* __restrict__ row_off,
    const uint2* __restrict__ epack, float* __restrict__ agg, int nN)
{
    int w    = (blockIdx.x * 256 + threadIdx.x) >> 6;
    int lane = threadIdx.x & 63;
    if (w >= nN) return;
    int s0 = row_off[w], s1 = row_off[w + 1];
    float acc = agg[(size_t)w * 64 + lane];
    const unsigned int un = (unsigned int)nN;
    for (int base = s0; base < s1; base += 64) {
        int m = min(64, s1 - base);
        unsigned int pk = 0; float wv = 0.f;
        if (lane < m) {
            uint2 pw = epack[base + lane];
            pk = pw.x; wv = __uint_as_float(pw.y);
        }
        int j = 0;
        for (; j + 8 <= m; j += 8) {
            unsigned int p0 = __shfl(pk, j + 0, 64), p1 = __shfl(pk, j + 1, 64);
            unsigned int p2 = __shfl(pk, j + 2, 64), p3 = __shfl(pk, j + 3, 64);
            unsigned int p4 = __shfl(pk, j + 4, 64), p5 = __shfl(pk, j + 5, 64);
            unsigned int p6 = __shfl(pk, j + 6, 64), p7 = __shfl(pk, j + 7, 64);
            float q0 = __shfl(wv, j + 0, 64), q1 = __shfl(wv, j + 1, 64);
            float q2 = __shfl(wv, j + 2, 64), q3 = __shfl(wv, j + 3, 64);
            float q4 = __shfl(wv, j + 4, 64), q5 = __shfl(wv, j + 5, 64);
            float q6 = __shfl(wv, j + 6, 64), q7 = __shfl(wv, j + 7, 64);
            ushort v0 = h[(((p0 >> 20) & 7) * un + (p0 & 0xFFFFFu)) * 64u + lane];
            ushort v1 = h[(((p1 >> 20) & 7) * un + (p1 & 0xFFFFFu)) * 64u + lane];
            ushort v2 = h[(((p2 >> 20) & 7) * un + (p2 & 0xFFFFFu)) * 64u + lane];
            ushort v3 = h[(((p3 >> 20) & 7) * un + (p3 & 0xFFFFFu)) * 64u + lane];
            ushort v4 = h[(((p4 >> 20) & 7) * un + (p4 & 0xFFFFFu)) * 64u + lane];
            ushort v5 = h[(((p5 >> 20) & 7) * un + (p5 & 0xFFFFFu)) * 64u + lane];
            ushort v6 = h[(((p6 >> 20) & 7) * un + (p6 & 0xFFFFFu)) * 64u + lane];
            ushort v7 = h[(((p7 >> 20) & 7) * un + (p7 & 0xFFFFFu)) * 64u + lane];
            acc = fmaf(q0, bf2f(v0), acc); acc = fmaf(q1, bf2f(v1), acc);
            acc = fmaf(q2, bf2f(v2), acc); acc = fmaf(q3, bf2f(v3), acc);
            acc = fmaf(q4, bf2f(v4), acc); acc = fmaf(q5, bf2f(v5), acc);
            acc = fmaf(q6, bf2f(v6), acc); acc = fmaf(q7, bf2f(v7), acc);
        }
        for (; j < m; ++j) {
            unsigned int pj = __shfl(pk, j, 64);
            float        wj = __shfl(wv, j, 64);
            ushort v = h[(((pj >> 20) & 7) * un + (pj & 0xFFFFFu)) * 64u + lane];
            acc = fmaf(wj, bf2f(v), acc);
        }
    }
    agg[(size_t)w * 64 + lane] = acc;
}

// ---------------------------------------------------------------------------
// Gather aggregation, C=40: lanes 0..39 accumulate; same 8-wide pipeline.
// ---------------------------------------------------------------------------
__global__ __launch_bounds__(256) void gather_d40(
    const ushort* __restrict__ h, const int* __restrict__ row_off,
    const uint2* __restrict__ epack, float* __restrict__ agg, int nN)
{
    int w    = (blockIdx.x * 256 + threadIdx.x) >> 6;
    int lane = threadIdx.x & 63;
    if (w >= nN) return;
    int s0 = row_off[w], s1 = row_off[w + 1];
    float acc = 0.f;
    if (lane < 40) acc = agg[(size_t)w * 40 + lane];
    const unsigned int un = (unsigned int)nN;
    for (int base = s0; base < s1; base += 64) {
        int m = min(64, s1 - base);
        unsigned int pk = 0; float wv = 0.f;
        if (lane < m) {
            uint2 pw = epack[base + lane];
            pk = pw.x; wv = __uint_as_float(pw.y);
        }
        int j = 0;
        for (; j + 8 <= m; j += 8) {
            unsigned int p0 = __shfl(pk, j + 0, 64), p1 = __shfl(pk, j + 1, 64);
            unsigned int p2 = __shfl(pk, j + 2, 64), p3 = __shfl(pk, j + 3, 64);
            unsigned int p4 = __shfl(pk, j + 4, 64), p5 = __shfl(pk, j + 5, 64);
            unsigned int p6 = __shfl(pk, j + 6, 64), p7 = __shfl(pk, j + 7, 64);
            float q0 = __shfl(wv, j + 0, 64), q1 = __shfl(wv, j + 1, 64);
            float q2 = __shfl(wv, j + 2, 64), q3 = __shfl(wv, j + 3, 64);
            float q4 = __shfl(wv, j + 4, 64), q5 = __shfl(wv, j + 5, 64);
            float q6 = __shfl(wv, j + 6, 64), q7 = __shfl(wv, j + 7, 64);
            if (lane < 40) {
                ushort v0 = h[(((p0 >> 20) & 7) * un + (p0 & 0xFFFFFu)) * 40u + lane];
                ushort v1 = h[(((p1 >> 20) & 7) * un + (p1 & 0xFFFFFu)) * 40u + lane];
                ushort v2 = h[(((p2 >> 20) & 7) * un + (p2 & 0xFFFFFu)) * 40u + lane];
                ushort v3 = h[(((p3 >> 20) & 7) * un + (p3 & 0xFFFFFu)) * 40u + lane];
                ushort v4 = h[(((p4 >> 20) & 7) * un + (p4 & 0xFFFFFu)) * 40u + lane];
                ushort v5 = h[(((p5 >> 20) & 7) * un + (p5 & 0xFFFFFu)) * 40u + lane];
                ushort v6 = h[(((p6 >> 20) & 7) * un + (p6 & 0xFFFFFu)) * 40u + lane];
                ushort v7 = h[(((p7 >> 20) & 7) * un + (p7 & 0xFFFFFu)) * 40u + lane];
                acc = fmaf(q0, bf2f(v0), acc); acc = fmaf(q1, bf2f(v1), acc);
                acc = fmaf(q2, bf2f(v2), acc); acc = fmaf(q3, bf2f(v3), acc);
                acc = fmaf(q4, bf2f(v4), acc); acc = fmaf(q5, bf2f(v5), acc);
                acc = fmaf(q6, bf2f(v6), acc); acc = fmaf(q7, bf2f(v7), acc);
            }
        }
        for (; j < m; ++j) {
            unsigned int pj = __shfl(pk, j, 64);
            float        wj = __shfl(wv, j, 64);
            if (lane < 40) {
                ushort v = h[(((pj >> 20) & 7) * un + (pj & 0xFFFFFu)) * 40u + lane];
                acc = fmaf(wj, bf2f(v), acc);
            }
        }
    }
    if (lane < 40) agg[(size_t)w * 40 + lane] = acc;
}

// ---------------------------------------------------------------------------
// Epilogue: (log_softmax(out), out)
// ---------------------------------------------------------------------------
__global__ __launch_bounds__(256) void logsoftmax_out(
    const float* __restrict__ agg2, float* __restrict__ out, int nN)
{
    int w    = (blockIdx.x * 256 + threadIdx.x) >> 6;
    int lane = threadIdx.x & 63;
    if (w >= nN) return;
    float v = -INFINITY;
    if (lane < 40) v = agg2[(size_t)w * 40 + lane];
    float m = v;
    #pragma unroll
    for (int o = 32; o > 0; o >>= 1) m = fmaxf(m, __shfl_xor(m, o, 64));
    float ex = (lane < 40) ? expf(v - m) : 0.f;
    float s = ex;
    #pragma unroll
    for (int o = 32; o > 0; o >>= 1) s += __shfl_xor(s, o, 64);
    float lse = logf(s) + m;
    if (lane < 40) {
        out[(size_t)w * 40 + lane] = v - lse;
        out[(size_t)nN * 40 + (size_t)w * 40 + lane] = v;
    }
}

// ---------------------------------------------------------------------------
extern "C" void kernel_launch(void* const* d_in, const int* in_sizes, int n_in,
                              void* d_out, int out_size, void* d_ws, size_t ws_size,
                              hipStream_t stream)
{
    const float* x       = (const float*)d_in[0];
    const int*   eidx    = (const int*)  d_in[1];
    const float* ew      = (const float*)d_in[2];
    const int*   ec      = (const int*)  d_in[3];
    const float* W1_rel  = (const float*)d_in[4];
    const float* W1_root = (const float*)d_in[5];
    const float* b1      = (const float*)d_in[6];
    const float* W2_rel  = (const float*)d_in[7];
    const float* W2_root = (const float*)d_in[8];
    const float* b2      = (const float*)d_in[9];

    const int nN = in_sizes[0] / 128;   // 100000
    const int nE = in_sizes[2];         // 3200000
    const int* src = eidx;
    const int* dst = eidx + nE;
    const int nB = (nN + BKT_NODES - 1) / BKT_NODES;

    char* w8 = (char*)d_ws;
    size_t off = 0;
    auto alloc = [&](size_t bytes) {
        void* p = w8 + off;
        off += (bytes + 255) & ~(size_t)255;
        return p;
    };
    ushort* h      = (ushort*)alloc((size_t)RELS * nN * 64 * 2);
    ushort* xb     = (ushort*)alloc((size_t)nN * 128 * 2);
    float*  agg1   = (float*) alloc((size_t)nN * 64 * 4);
    float*  agg2   = (float*) alloc((size_t)nN * 40 * 4);
    int*    counts = (int*)   alloc((size_t)nN * 4);
    int*    row_off= (int*)   alloc(((size_t)nN + 1) * 4);
    int*    cursor = (int*)   alloc((size_t)nN * 4);
    int*    bsum   = (int*)   alloc(4096);
    int*    bbase  = (int*)   alloc(4096);
    int*    bcur   = (int*)   alloc((size_t)nB * 4);
    uint2*  epack  = (uint2*) alloc((size_t)nE * 8);
    ushort* w1t    = (ushort*)alloc((size_t)9 * 64 * 128 * 2);
    ushort* w2t    = (ushort*)alloc((size_t)9 * 48 * 64 * 2);
    size_t  base_need = off;
    uint2*  epackA = (uint2*)alloc((size_t)nE * 8);
    const bool bucketed = (off <= ws_size);
    ushort* y1b = xb;   // x bf16 dead after layer-1 GEMMs

    const dim3 blk(256);
    const int NB_scan     = (nN + 255) / 256;
    const int gemm_blocks = (nN + 63) / 64;
    const int edge_blocks = (nE + 255) / 256;
    const int wave_blocks = (int)(((size_t)nN * 64 + 255) / 256);
    const int ls_blocks   = (nN + 3) / 4;
    (void)base_need;

    // ---- CSR build
    hipMemsetAsync(counts, 0, (size_t)nN * 4, stream);
    hist_dst<<<edge_blocks, blk, 0, stream>>>(dst, counts, nE);
    scan_partial<<<NB_scan, blk, 0, stream>>>(counts, bsum, nN);
    scan_base<<<1, dim3(512), 0, stream>>>(bsum, bbase, NB_scan, row_off, nN);
    scan_final<<<NB_scan, blk, 0, stream>>>(counts, bbase, row_off, cursor, nN);
    if (bucketed) {
        init_bcur<<<(nB + 255) / 256, blk, 0, stream>>>(row_off, bcur, nB, nN);
        bucket_fill<<<edge_blocks, blk, 0, stream>>>(src, dst, ew, ec, bcur, epackA, nE);
        reorder_bucket<<<nB, blk, 0, stream>>>(epackA, row_off, cursor, epack, nN);
    } else {
        fill_csr<<<edge_blocks, blk, 0, stream>>>(src, dst, ew, ec, cursor, epack, nE);
    }

    // ---- weight/input prep (bf16)
    cast_f32_bf16x4<<<(nN * 128 / 4 + 255) / 256, blk, 0, stream>>>(x, xb, nN * 128 / 4);
    conv_w1<<<(9 * 64 * 128 + 255) / 256, blk, 0, stream>>>(W1_rel, W1_root, w1t);
    conv_w2<<<(9 * 48 * 64 + 255) / 256, blk, 0, stream>>>(W2_rel, W2_root, w2t);

    // ---- Layer 1
    gemm1_mfma<<<dim3(gemm_blocks, 9), blk, 0, stream>>>(xb, w1t, h, agg1, b1, nN);
    gather_d64<<<wave_blocks, blk, 0, stream>>>(h, row_off, epack, agg1, nN);

    // ---- Layer 2
    cast_relu_bf16x4<<<(nN * 64 / 4 + 255) / 256, blk, 0, stream>>>(agg1, y1b, nN * 64 / 4);
    gemm2_mfma<<<dim3(gemm_blocks, 9), blk, 0, stream>>>(y1b, w2t, h, agg2, b2, nN);
    gather_d40<<<wave_blocks, blk, 0, stream>>>(h, row_off, epack, agg2, nN);

    // ---- Epilogue
    logsoftmax_out<<<ls_blocks, blk, 0, stream>>>(agg2, (float*)d_out, nN);
}

// Round 5
// 622.188 us; speedup vs baseline: 1.9952x; 1.9952x over previous
//
#include <hip/hip_runtime.h>
#include <hip/hip_bf16.h>
#include <cmath>

// WRGCN: 2-layer weighted relational GCN.
// N=100000, E=3200000, R=8, F_IN=128, DIMS=64, C=40.
// dst-CSR (direct per-node-cursor fill: 100K cursors keeps atomic contention
// ~32/address; bucketed fill with 782 cursors measured 749us of same-address
// atomic serialization -- do NOT reduce cursor count), 8-wide-pipelined
// gathers, all GEMMs (incl. root) on bf16 MFMA.

#define RELS 8

typedef __attribute__((ext_vector_type(8))) short bf16x8;
typedef __attribute__((ext_vector_type(4))) float f32x4;

static __device__ __forceinline__ ushort f2bf(float f) {
    __hip_bfloat16 b = __float2bfloat16(f);
    return *reinterpret_cast<ushort*>(&b);
}
static __device__ __forceinline__ float bf2f(ushort u) {
    return __uint_as_float(((unsigned int)u) << 16);
}

// ---------------------------------------------------------------------------
// Casts / weight prep
// ---------------------------------------------------------------------------
__global__ __launch_bounds__(256) void cast_f32_bf16x4(
    const float* __restrict__ in, ushort* __restrict__ out, int n4)
{
    int i = blockIdx.x * 256 + threadIdx.x;
    if (i >= n4) return;
    float4 v = ((const float4*)in)[i];
    ushort4 o;
    o.x = f2bf(v.x); o.y = f2bf(v.y); o.z = f2bf(v.z); o.w = f2bf(v.w);
    ((ushort4*)out)[i] = o;
}

__global__ __launch_bounds__(256) void cast_relu_bf16x4(
    const float* __restrict__ in, ushort* __restrict__ out, int n4)
{
    int i = blockIdx.x * 256 + threadIdx.x;
    if (i >= n4) return;
    float4 v = ((const float4*)in)[i];
    ushort4 o;
    o.x = f2bf(fmaxf(v.x, 0.f)); o.y = f2bf(fmaxf(v.y, 0.f));
    o.z = f2bf(fmaxf(v.z, 0.f)); o.w = f2bf(fmaxf(v.w, 0.f));
    ((ushort4*)out)[i] = o;
}

// w1t[r][c][k]: r in [0,9): r<8 from W1_rel [R][128][64]; r==8 from W1_root.
__global__ __launch_bounds__(256) void conv_w1(
    const float* __restrict__ Wrel, const float* __restrict__ Wroot,
    ushort* __restrict__ wt)
{
    int i = blockIdx.x * 256 + threadIdx.x;
    if (i >= 9 * 64 * 128) return;
    int r = i >> 13, c = (i >> 7) & 63, k = i & 127;
    float v = (r < 8) ? Wrel[((size_t)r * 128 + k) * 64 + c]
                      : Wroot[(size_t)k * 64 + c];
    wt[i] = f2bf(v);
}

// w2t[r][c][k]: r in [0,9), c in [0,48) (pad 40..47 = 0), k in [0,64).
__global__ __launch_bounds__(256) void conv_w2(
    const float* __restrict__ Wrel, const float* __restrict__ Wroot,
    ushort* __restrict__ wt)
{
    int i = blockIdx.x * 256 + threadIdx.x;
    if (i >= 9 * 48 * 64) return;
    int r = i / (48 * 64), rem = i - r * (48 * 64);
    int c = rem >> 6, k = rem & 63;
    float v = 0.f;
    if (c < 40)
        v = (r < 8) ? Wrel[((size_t)r * 64 + k) * 40 + c]
                    : Wroot[(size_t)k * 40 + c];
    wt[i] = f2bf(v);
}

// ---------------------------------------------------------------------------
// Layer-1 GEMMs (MFMA bf16), blockIdx.y in [0,9):
//   y<8 : h[y][n][0:64] = xb[n][0:128] @ W1_rel[y]      (bf16 out)
//   y==8: agg1[n][0:64] = xb[n][0:128] @ W1_root + b1   (f32 out)
// ---------------------------------------------------------------------------
__global__ __launch_bounds__(256) void gemm1_mfma(
    const ushort* __restrict__ xb, const ushort* __restrict__ w1t,
    ushort* __restrict__ hout, float* __restrict__ agg1,
    const float* __restrict__ b1, int nN)
{
    __shared__ ushort xs[64 * 128];
    __shared__ ushort wt[64 * 128];
    const int y    = blockIdx.y;
    const int tid  = threadIdx.x;
    const int n0   = blockIdx.x * 64;
    const int nmax = nN - n0;
    const bool isroot = (y == 8);
    ushort* out = hout + (size_t)y * nN * 64;
    const ushort* wsrc = w1t + (size_t)y * 64 * 128;

    for (int i = tid; i < 1024; i += 256) {
        int row = i >> 4, ch = i & 15;
        uint4 v = make_uint4(0u, 0u, 0u, 0u);
        if (row < nmax)
            v = *(const uint4*)(xb + (size_t)(n0 + row) * 128 + ch * 8);
        int off = (row * 256 + ch * 16) ^ ((row & 7) << 4);
        *(uint4*)((char*)xs + off) = v;
    }
    for (int i = tid; i < 1024; i += 256) {
        int row = i >> 4, ch = i & 15;
        uint4 v = *(const uint4*)(wsrc + (size_t)row * 128 + ch * 8);
        int off = (row * 256 + ch * 16) ^ ((row & 7) << 4);
        *(uint4*)((char*)wt + off) = v;
    }
    __syncthreads();

    const int wv   = tid >> 6;
    const int lane = tid & 63;
    const int lr   = wv * 16 + (lane & 15);
    const int kgb  = (lane >> 4) * 8;

    f32x4 acc[4] = {{0.f,0.f,0.f,0.f},{0.f,0.f,0.f,0.f},
                    {0.f,0.f,0.f,0.f},{0.f,0.f,0.f,0.f}};

    #pragma unroll
    for (int ks = 0; ks < 4; ++ks) {
        int kb = (ks * 32 + kgb) * 2;
        int aoff = (lr * 256 + kb) ^ ((lr & 7) << 4);
        bf16x8 a = *(const bf16x8*)((const char*)xs + aoff);
        #pragma unroll
        for (int ct = 0; ct < 4; ++ct) {
            int col = ct * 16 + (lane & 15);
            int boff = (col * 256 + kb) ^ ((col & 7) << 4);
            bf16x8 b = *(const bf16x8*)((const char*)wt + boff);
            acc[ct] = __builtin_amdgcn_mfma_f32_16x16x32_bf16(a, b, acc[ct], 0, 0, 0);
        }
    }

    #pragma unroll
    for (int ct = 0; ct < 4; ++ct) {
        int col = ct * 16 + (lane & 15);
        #pragma unroll
        for (int reg = 0; reg < 4; ++reg) {
            int row = wv * 16 + (lane >> 4) * 4 + reg;
            if (row < nmax) {
                if (isroot)
                    agg1[(size_t)(n0 + row) * 64 + col] = acc[ct][reg] + b1[col];
                else
                    out[(size_t)(n0 + row) * 64 + col] = f2bf(acc[ct][reg]);
            }
        }
    }
}

// ---------------------------------------------------------------------------
// Layer-2 GEMMs (MFMA bf16), blockIdx.y in [0,9):
//   y<8 : h2[y][n][0:40] = y1b[n][0:64] @ W2_rel[y]     (bf16 out)
//   y==8: agg2[n][0:40] = y1b[n][0:64] @ W2_root + b2   (f32 out)
// ---------------------------------------------------------------------------
__global__ __launch_bounds__(256) void gemm2_mfma(
    const ushort* __restrict__ y1b, const ushort* __restrict__ w2t,
    ushort* __restrict__ hout, float* __restrict__ agg2,
    const float* __restrict__ b2, int nN)
{
    __shared__ ushort ys[64 * 64];
    __shared__ ushort wt[48 * 64];
    const int y    = blockIdx.y;
    const int tid  = threadIdx.x;
    const int n0   = blockIdx.x * 64;
    const int nmax = nN - n0;
    const bool isroot = (y == 8);
    ushort* out = hout + (size_t)y * nN * 40;
    const ushort* wsrc = w2t + (size_t)y * 48 * 64;

    for (int i = tid; i < 512; i += 256) {
        int row = i >> 3, ch = i & 7;
        uint4 v = make_uint4(0u, 0u, 0u, 0u);
        if (row < nmax)
            v = *(const uint4*)(y1b + (size_t)(n0 + row) * 64 + ch * 8);
        int off = (row * 128 + ch * 16) ^ ((row & 7) << 4);
        *(uint4*)((char*)ys + off) = v;
    }
    for (int i = tid; i < 384; i += 256) {
        int row = i >> 3, ch = i & 7;
        uint4 v = *(const uint4*)(wsrc + (size_t)row * 64 + ch * 8);
        int off = (row * 128 + ch * 16) ^ ((row & 7) << 4);
        *(uint4*)((char*)wt + off) = v;
    }
    __syncthreads();

    const int wv   = tid >> 6;
    const int lane = tid & 63;
    const int lr   = wv * 16 + (lane & 15);
    const int kgb  = (lane >> 4) * 8;

    f32x4 acc[3] = {{0.f,0.f,0.f,0.f},{0.f,0.f,0.f,0.f},{0.f,0.f,0.f,0.f}};

    #pragma unroll
    for (int ks = 0; ks < 2; ++ks) {
        int kb = (ks * 32 + kgb) * 2;
        int aoff = (lr * 128 + kb) ^ ((lr & 7) << 4);
        bf16x8 a = *(const bf16x8*)((const char*)ys + aoff);
        #pragma unroll
        for (int ct = 0; ct < 3; ++ct) {
            int col = ct * 16 + (lane & 15);
            int boff = (col * 128 + kb) ^ ((col & 7) << 4);
            bf16x8 b = *(const bf16x8*)((const char*)wt + boff);
            acc[ct] = __builtin_amdgcn_mfma_f32_16x16x32_bf16(a, b, acc[ct], 0, 0, 0);
        }
    }

    #pragma unroll
    for (int ct = 0; ct < 3; ++ct) {
        int col = ct * 16 + (lane & 15);
        if (col < 40) {
            #pragma unroll
            for (int reg = 0; reg < 4; ++reg) {
                int row = wv * 16 + (lane >> 4) * 4 + reg;
                if (row < nmax) {
                    if (isroot)
                        agg2[(size_t)(n0 + row) * 40 + col] = acc[ct][reg] + b2[col];
                    else
                        out[(size_t)(n0 + row) * 40 + col] = f2bf(acc[ct][reg]);
                }
            }
        }
    }
}

// ---------------------------------------------------------------------------
// CSR build: histogram -> 3-phase exclusive scan -> direct cursor fill
// payload pk: bits 0..19 src, 20..22 color
// ---------------------------------------------------------------------------
__global__ __launch_bounds__(256) void hist_dst(
    const int* __restrict__ dst, int* __restrict__ counts, int nE)
{
    int e = blockIdx.x * 256 + threadIdx.x;
    if (e < nE) atomicAdd(&counts[dst[e]], 1);
}

__global__ __launch_bounds__(256) void scan_partial(
    const int* __restrict__ counts, int* __restrict__ bsum, int nN)
{
    __shared__ int s[256];
    int t = threadIdx.x;
    int i = blockIdx.x * 256 + t;
    int v = (i < nN) ? counts[i] : 0;
    s[t] = v; __syncthreads();
    for (int o = 1; o < 256; o <<= 1) {
        int u = (t >= o) ? s[t - o] : 0;
        __syncthreads(); s[t] += u; __syncthreads();
    }
    if (t == 255) bsum[blockIdx.x] = s[255];
}

__global__ __launch_bounds__(512) void scan_base(
    const int* __restrict__ bsum, int* __restrict__ bbase, int nb,
    int* __restrict__ row_off, int nN)
{
    __shared__ int s[512];
    int t = threadIdx.x;
    int v = (t < nb) ? bsum[t] : 0;
    s[t] = v; __syncthreads();
    for (int o = 1; o < 512; o <<= 1) {
        int u = (t >= o) ? s[t - o] : 0;
        __syncthreads(); s[t] += u; __syncthreads();
    }
    if (t < nb) bbase[t] = s[t] - v;
    if (t == nb - 1) row_off[nN] = s[t];
}

__global__ __launch_bounds__(256) void scan_final(
    const int* __restrict__ counts, const int* __restrict__ bbase,
    int* __restrict__ row_off, int* __restrict__ cursor, int nN)
{
    __shared__ int s[256];
    int t = threadIdx.x;
    int i = blockIdx.x * 256 + t;
    int v = (i < nN) ? counts[i] : 0;
    s[t] = v; __syncthreads();
    for (int o = 1; o < 256; o <<= 1) {
        int u = (t >= o) ? s[t - o] : 0;
        __syncthreads(); s[t] += u; __syncthreads();
    }
    if (i < nN) {
        int off = bbase[blockIdx.x] + s[t] - v;
        row_off[i] = off;
        cursor[i]  = off;
    }
}

__global__ __launch_bounds__(256) void fill_csr(
    const int* __restrict__ src, const int* __restrict__ dst,
    const float* __restrict__ ew, const int* __restrict__ ec,
    int* __restrict__ cursor, uint2* __restrict__ epack, int nE)
{
    int e = blockIdx.x * 256 + threadIdx.x;
    if (e >= nE) return;
    int p = atomicAdd(&cursor[dst[e]], 1);
    epack[p] = make_uint2((unsigned int)src[e] | ((unsigned int)ec[e] << 20),
                          __float_as_uint(ew[e]));
}

// ---------------------------------------------------------------------------
// Gather aggregation, DIMS=64: one wave per dst node, lane = dim.
// 8-wide software pipeline: 8 independent loads in flight per wave.
// ---------------------------------------------------------------------------
__global__ __launch_bounds__(256) void gather_d64(
    const ushort* __restrict__ h, const int* __restrict__ row_off,
    const uint2* __restrict__ epack, float* __restrict__ agg, int nN)
{
    int w    = (blockIdx.x * 256 + threadIdx.x) >> 6;
    int lane = threadIdx.x & 63;
    if (w >= nN) return;
    int s0 = row_off[w], s1 = row_off[w + 1];
    float acc = agg[(size_t)w * 64 + lane];
    const unsigned int un = (unsigned int)nN;
    for (int base = s0; base < s1; base += 64) {
        int m = min(64, s1 - base);
        unsigned int pk = 0; float wv = 0.f;
        if (lane < m) {
            uint2 pw = epack[base + lane];
            pk = pw.x; wv = __uint_as_float(pw.y);
        }
        int j = 0;
        for (; j + 8 <= m; j += 8) {
            unsigned int p0 = __shfl(pk, j + 0, 64), p1 = __shfl(pk, j + 1, 64);
            unsigned int p2 = __shfl(pk, j + 2, 64), p3 = __shfl(pk, j + 3, 64);
            unsigned int p4 = __shfl(pk, j + 4, 64), p5 = __shfl(pk, j + 5, 64);
            unsigned int p6 = __shfl(pk, j + 6, 64), p7 = __shfl(pk, j + 7, 64);
            float q0 = __shfl(wv, j + 0, 64), q1 = __shfl(wv, j + 1, 64);
            float q2 = __shfl(wv, j + 2, 64), q3 = __shfl(wv, j + 3, 64);
            float q4 = __shfl(wv, j + 4, 64), q5 = __shfl(wv, j + 5, 64);
            float q6 = __shfl(wv, j + 6, 64), q7 = __shfl(wv, j + 7, 64);
            ushort v0 = h[(((p0 >> 20) & 7) * un + (p0 & 0xFFFFFu)) * 64u + lane];
            ushort v1 = h[(((p1 >> 20) & 7) * un + (p1 & 0xFFFFFu)) * 64u + lane];
            ushort v2 = h[(((p2 >> 20) & 7) * un + (p2 & 0xFFFFFu)) * 64u + lane];
            ushort v3 = h[(((p3 >> 20) & 7) * un + (p3 & 0xFFFFFu)) * 64u + lane];
            ushort v4 = h[(((p4 >> 20) & 7) * un + (p4 & 0xFFFFFu)) * 64u + lane];
            ushort v5 = h[(((p5 >> 20) & 7) * un + (p5 & 0xFFFFFu)) * 64u + lane];
            ushort v6 = h[(((p6 >> 20) & 7) * un + (p6 & 0xFFFFFu)) * 64u + lane];
            ushort v7 = h[(((p7 >> 20) & 7) * un + (p7 & 0xFFFFFu)) * 64u + lane];
            acc = fmaf(q0, bf2f(v0), acc); acc = fmaf(q1, bf2f(v1), acc);
            acc = fmaf(q2, bf2f(v2), acc); acc = fmaf(q3, bf2f(v3), acc);
            acc = fmaf(q4, bf2f(v4), acc); acc = fmaf(q5, bf2f(v5), acc);
            acc = fmaf(q6, bf2f(v6), acc); acc = fmaf(q7, bf2f(v7), acc);
        }
        for (; j < m; ++j) {
            unsigned int pj = __shfl(pk, j, 64);
            float        wj = __shfl(wv, j, 64);
            ushort v = h[(((pj >> 20) & 7) * un + (pj & 0xFFFFFu)) * 64u + lane];
            acc = fmaf(wj, bf2f(v), acc);
        }
    }
    agg[(size_t)w * 64 + lane] = acc;
}

// ---------------------------------------------------------------------------
// Gather aggregation, C=40: lanes 0..39 accumulate; same 8-wide pipeline.
// ---------------------------------------------------------------------------
__global__ __launch_bounds__(256) void gather_d40(
    const ushort* __restrict__ h, const int* __restrict__ row_off,
    const uint2* __restrict__ epack, float* __restrict__ agg, int nN)
{
    int w    = (blockIdx.x * 256 + threadIdx.x) >> 6;
    int lane = threadIdx.x & 63;
    if (w >= nN) return;
    int s0 = row_off[w], s1 = row_off[w + 1];
    float acc = 0.f;
    if (lane < 40) acc = agg[(size_t)w * 40 + lane];
    const unsigned int un = (unsigned int)nN;
    for (int base = s0; base < s1; base += 64) {
        int m = min(64, s1 - base);
        unsigned int pk = 0; float wv = 0.f;
        if (lane < m) {
            uint2 pw = epack[base + lane];
            pk = pw.x; wv = __uint_as_float(pw.y);
        }
        int j = 0;
        for (; j + 8 <= m; j += 8) {
            unsigned int p0 = __shfl(pk, j + 0, 64), p1 = __shfl(pk, j + 1, 64);
            unsigned int p2 = __shfl(pk, j + 2, 64), p3 = __shfl(pk, j + 3, 64);
            unsigned int p4 = __shfl(pk, j + 4, 64), p5 = __shfl(pk, j + 5, 64);
            unsigned int p6 = __shfl(pk, j + 6, 64), p7 = __shfl(pk, j + 7, 64);
            float q0 = __shfl(wv, j + 0, 64), q1 = __shfl(wv, j + 1, 64);
            float q2 = __shfl(wv, j + 2, 64), q3 = __shfl(wv, j + 3, 64);
            float q4 = __shfl(wv, j + 4, 64), q5 = __shfl(wv, j + 5, 64);
            float q6 = __shfl(wv, j + 6, 64), q7 = __shfl(wv, j + 7, 64);
            if (lane < 40) {
                ushort v0 = h[(((p0 >> 20) & 7) * un + (p0 & 0xFFFFFu)) * 40u + lane];
                ushort v1 = h[(((p1 >> 20) & 7) * un + (p1 & 0xFFFFFu)) * 40u + lane];
                ushort v2 = h[(((p2 >> 20) & 7) * un + (p2 & 0xFFFFFu)) * 40u + lane];
                ushort v3 = h[(((p3 >> 20) & 7) * un + (p3 & 0xFFFFFu)) * 40u + lane];
                ushort v4 = h[(((p4 >> 20) & 7) * un + (p4 & 0xFFFFFu)) * 40u + lane];
                ushort v5 = h[(((p5 >> 20) & 7) * un + (p5 & 0xFFFFFu)) * 40u + lane];
                ushort v6 = h[(((p6 >> 20) & 7) * un + (p6 & 0xFFFFFu)) * 40u + lane];
                ushort v7 = h[(((p7 >> 20) & 7) * un + (p7 & 0xFFFFFu)) * 40u + lane];
                acc = fmaf(q0, bf2f(v0), acc); acc = fmaf(q1, bf2f(v1), acc);
                acc = fmaf(q2, bf2f(v2), acc); acc = fmaf(q3, bf2f(v3), acc);
                acc = fmaf(q4, bf2f(v4), acc); acc = fmaf(q5, bf2f(v5), acc);
                acc = fmaf(q6, bf2f(v6), acc); acc = fmaf(q7, bf2f(v7), acc);
            }
        }
        for (; j < m; ++j) {
            unsigned int pj = __shfl(pk, j, 64);
            float        wj = __shfl(wv, j, 64);
            if (lane < 40) {
                ushort v = h[(((pj >> 20) & 7) * un + (pj & 0xFFFFFu)) * 40u + lane];
                acc = fmaf(wj, bf2f(v), acc);
            }
        }
    }
    if (lane < 40) agg[(size_t)w * 40 + lane] = acc;
}

// ---------------------------------------------------------------------------
// Epilogue: (log_softmax(out), out)
// ---------------------------------------------------------------------------
__global__ __launch_bounds__(256) void logsoftmax_out(
    const float* __restrict__ agg2, float* __restrict__ out, int nN)
{
    int w    = (blockIdx.x * 256 + threadIdx.x) >> 6;
    int lane = threadIdx.x & 63;
    if (w >= nN) return;
    float v = -INFINITY;
    if (lane < 40) v = agg2[(size_t)w * 40 + lane];
    float m = v;
    #pragma unroll
    for (int o = 32; o > 0; o >>= 1) m = fmaxf(m, __shfl_xor(m, o, 64));
    float ex = (lane < 40) ? expf(v - m) : 0.f;
    float s = ex;
    #pragma unroll
    for (int o = 32; o > 0; o >>= 1) s += __shfl_xor(s, o, 64);
    float lse = logf(s) + m;
    if (lane < 40) {
        out[(size_t)w * 40 + lane] = v - lse;
        out[(size_t)nN * 40 + (size_t)w * 40 + lane] = v;
    }
}

// ---------------------------------------------------------------------------
extern "C" void kernel_launch(void* const* d_in, const int* in_sizes, int n_in,
                              void* d_out, int out_size, void* d_ws, size_t ws_size,
                              hipStream_t stream)
{
    const float* x       = (const float*)d_in[0];
    const int*   eidx    = (const int*)  d_in[1];
    const float* ew      = (const float*)d_in[2];
    const int*   ec      = (const int*)  d_in[3];
    const float* W1_rel  = (const float*)d_in[4];
    const float* W1_root = (const float*)d_in[5];
    const float* b1      = (const float*)d_in[6];
    const float* W2_rel  = (const float*)d_in[7];
    const float* W2_root = (const float*)d_in[8];
    const float* b2      = (const float*)d_in[9];

    const int nN = in_sizes[0] / 128;   // 100000
    const int nE = in_sizes[2];         // 3200000
    const int* src = eidx;
    const int* dst = eidx + nE;

    char* w8 = (char*)d_ws;
    size_t off = 0;
    auto alloc = [&](size_t bytes) {
        void* p = w8 + off;
        off += (bytes + 255) & ~(size_t)255;
        return p;
    };
    ushort* h      = (ushort*)alloc((size_t)RELS * nN * 64 * 2);
    ushort* xb     = (ushort*)alloc((size_t)nN * 128 * 2);
    float*  agg1   = (float*) alloc((size_t)nN * 64 * 4);
    float*  agg2   = (float*) alloc((size_t)nN * 40 * 4);
    int*    counts = (int*)   alloc((size_t)nN * 4);
    int*    row_off= (int*)   alloc(((size_t)nN + 1) * 4);
    int*    cursor = (int*)   alloc((size_t)nN * 4);
    int*    bsum   = (int*)   alloc(4096);
    int*    bbase  = (int*)   alloc(4096);
    uint2*  epack  = (uint2*) alloc((size_t)nE * 8);
    ushort* w1t    = (ushort*)alloc((size_t)9 * 64 * 128 * 2);
    ushort* w2t    = (ushort*)alloc((size_t)9 * 48 * 64 * 2);
    ushort* y1b    = xb;   // x bf16 dead after layer-1 GEMMs

    const dim3 blk(256);
    const int NB_scan     = (nN + 255) / 256;
    const int gemm_blocks = (nN + 63) / 64;
    const int edge_blocks = (nE + 255) / 256;
    const int wave_blocks = (int)(((size_t)nN * 64 + 255) / 256);
    const int ls_blocks   = (nN + 3) / 4;

    // ---- CSR build
    hipMemsetAsync(counts, 0, (size_t)nN * 4, stream);
    hist_dst<<<edge_blocks, blk, 0, stream>>>(dst, counts, nE);
    scan_partial<<<NB_scan, blk, 0, stream>>>(counts, bsum, nN);
    scan_base<<<1, dim3(512), 0, stream>>>(bsum, bbase, NB_scan, row_off, nN);
    scan_final<<<NB_scan, blk, 0, stream>>>(counts, bbase, row_off, cursor, nN);
    fill_csr<<<edge_blocks, blk, 0, stream>>>(src, dst, ew, ec, cursor, epack, nE);

    // ---- weight/input prep (bf16)
    cast_f32_bf16x4<<<(nN * 128 / 4 + 255) / 256, blk, 0, stream>>>(x, xb, nN * 128 / 4);
    conv_w1<<<(9 * 64 * 128 + 255) / 256, blk, 0, stream>>>(W1_rel, W1_root, w1t);
    conv_w2<<<(9 * 48 * 64 + 255) / 256, blk, 0, stream>>>(W2_rel, W2_root, w2t);

    // ---- Layer 1
    gemm1_mfma<<<dim3(gemm_blocks, 9), blk, 0, stream>>>(xb, w1t, h, agg1, b1, nN);
    gather_d64<<<wave_blocks, blk, 0, stream>>>(h, row_off, epack, agg1, nN);

    // ---- Layer 2
    cast_relu_bf16x4<<<(nN * 64 / 4 + 255) / 256, blk, 0, stream>>>(agg1, y1b, nN * 64 / 4);
    gemm2_mfma<<<dim3(gemm_blocks, 9), blk, 0, stream>>>(y1b, w2t, h, agg2, b2, nN);
    gather_d40<<<wave_blocks, blk, 0, stream>>>(h, row_off, epack, agg2, nN);

    // ---- Epilogue
    logsoftmax_out<<<ls_blocks, blk, 0, stream>>>(agg2, (float*)d_out, nN);
}

// Round 6
// 542.866 us; speedup vs baseline: 2.2867x; 1.1461x over previous
//
#include <hip/hip_runtime.h>
#include <hip/hip_bf16.h>
#include <cmath>

// WRGCN: 2-layer weighted relational GCN.
// N=100000, E=3200000, R=8, F_IN=128, DIMS=64, C=40.
// Lessons encoded here:
//  - scattered partial-line stores cost one full 64B line each regardless of
//    temporal locality (r4/r5 counters); coalescing happens only at wave issue
//    -> CSR fill must LDS-stage and flush linearly (multisplit).
//  - never funnel E atomics into few cursors (r4: 782 cursors -> 749us chain).
//    This fill uses NO global atomics: per-(block,bucket) counts + scan.
// 8-wide-pipelined gathers; all GEMMs (incl. root) on bf16 MFMA.

#define RELS 8
#define CH 4096       // edges per multisplit chunk
#define ST2CAP 6144   // stage-2 LDS staging capacity (mean 4096, +18 sigma)

typedef __attribute__((ext_vector_type(8))) short bf16x8;
typedef __attribute__((ext_vector_type(4))) float f32x4;

static __device__ __forceinline__ ushort f2bf(float f) {
    __hip_bfloat16 b = __float2bfloat16(f);
    return *reinterpret_cast<ushort*>(&b);
}
static __device__ __forceinline__ float bf2f(ushort u) {
    return __uint_as_float(((unsigned int)u) << 16);
}

// ---------------------------------------------------------------------------
// Casts / weight prep
// ---------------------------------------------------------------------------
__global__ __launch_bounds__(256) void cast_f32_bf16x4(
    const float* __restrict__ in, ushort* __restrict__ out, int n4)
{
    int i = blockIdx.x * 256 + threadIdx.x;
    if (i >= n4) return;
    float4 v = ((const float4*)in)[i];
    ushort4 o;
    o.x = f2bf(v.x); o.y = f2bf(v.y); o.z = f2bf(v.z); o.w = f2bf(v.w);
    ((ushort4*)out)[i] = o;
}

__global__ __launch_bounds__(256) void cast_relu_bf16x4(
    const float* __restrict__ in, ushort* __restrict__ out, int n4)
{
    int i = blockIdx.x * 256 + threadIdx.x;
    if (i >= n4) return;
    float4 v = ((const float4*)in)[i];
    ushort4 o;
    o.x = f2bf(fmaxf(v.x, 0.f)); o.y = f2bf(fmaxf(v.y, 0.f));
    o.z = f2bf(fmaxf(v.z, 0.f)); o.w = f2bf(fmaxf(v.w, 0.f));
    ((ushort4*)out)[i] = o;
}

// w1t[r][c][k]: r in [0,9): r<8 from W1_rel [R][128][64]; r==8 from W1_root.
__global__ __launch_bounds__(256) void conv_w1(
    const float* __restrict__ Wrel, const float* __restrict__ Wroot,
    ushort* __restrict__ wt)
{
    int i = blockIdx.x * 256 + threadIdx.x;
    if (i >= 9 * 64 * 128) return;
    int r = i >> 13, c = (i >> 7) & 63, k = i & 127;
    float v = (r < 8) ? Wrel[((size_t)r * 128 + k) * 64 + c]
                      : Wroot[(size_t)k * 64 + c];
    wt[i] = f2bf(v);
}

// w2t[r][c][k]: r in [0,9), c in [0,48) (pad 40..47 = 0), k in [0,64).
__global__ __launch_bounds__(256) void conv_w2(
    const float* __restrict__ Wrel, const float* __restrict__ Wroot,
    ushort* __restrict__ wt)
{
    int i = blockIdx.x * 256 + threadIdx.x;
    if (i >= 9 * 48 * 64) return;
    int r = i / (48 * 64), rem = i - r * (48 * 64);
    int c = rem >> 6, k = rem & 63;
    float v = 0.f;
    if (c < 40)
        v = (r < 8) ? Wrel[((size_t)r * 64 + k) * 40 + c]
                    : Wroot[(size_t)k * 40 + c];
    wt[i] = f2bf(v);
}

// ---------------------------------------------------------------------------
// Layer-1 GEMMs (MFMA bf16), blockIdx.y in [0,9):
//   y<8 : h[y][n][0:64] = xb[n][0:128] @ W1_rel[y]      (bf16 out)
//   y==8: agg1[n][0:64] = xb[n][0:128] @ W1_root + b1   (f32 out)
// ---------------------------------------------------------------------------
__global__ __launch_bounds__(256) void gemm1_mfma(
    const ushort* __restrict__ xb, const ushort* __restrict__ w1t,
    ushort* __restrict__ hout, float* __restrict__ agg1,
    const float* __restrict__ b1, int nN)
{
    __shared__ ushort xs[64 * 128];
    __shared__ ushort wt[64 * 128];
    const int y    = blockIdx.y;
    const int tid  = threadIdx.x;
    const int n0   = blockIdx.x * 64;
    const int nmax = nN - n0;
    const bool isroot = (y == 8);
    ushort* out = hout + (size_t)y * nN * 64;
    const ushort* wsrc = w1t + (size_t)y * 64 * 128;

    for (int i = tid; i < 1024; i += 256) {
        int row = i >> 4, ch = i & 15;
        uint4 v = make_uint4(0u, 0u, 0u, 0u);
        if (row < nmax)
            v = *(const uint4*)(xb + (size_t)(n0 + row) * 128 + ch * 8);
        int off = (row * 256 + ch * 16) ^ ((row & 7) << 4);
        *(uint4*)((char*)xs + off) = v;
    }
    for (int i = tid; i < 1024; i += 256) {
        int row = i >> 4, ch = i & 15;
        uint4 v = *(const uint4*)(wsrc + (size_t)row * 128 + ch * 8);
        int off = (row * 256 + ch * 16) ^ ((row & 7) << 4);
        *(uint4*)((char*)wt + off) = v;
    }
    __syncthreads();

    const int wv   = tid >> 6;
    const int lane = tid & 63;
    const int lr   = wv * 16 + (lane & 15);
    const int kgb  = (lane >> 4) * 8;

    f32x4 acc[4] = {{0.f,0.f,0.f,0.f},{0.f,0.f,0.f,0.f},
                    {0.f,0.f,0.f,0.f},{0.f,0.f,0.f,0.f}};

    #pragma unroll
    for (int ks = 0; ks < 4; ++ks) {
        int kb = (ks * 32 + kgb) * 2;
        int aoff = (lr * 256 + kb) ^ ((lr & 7) << 4);
        bf16x8 a = *(const bf16x8*)((const char*)xs + aoff);
        #pragma unroll
        for (int ct = 0; ct < 4; ++ct) {
            int col = ct * 16 + (lane & 15);
            int boff = (col * 256 + kb) ^ ((col & 7) << 4);
            bf16x8 b = *(const bf16x8*)((const char*)wt + boff);
            acc[ct] = __builtin_amdgcn_mfma_f32_16x16x32_bf16(a, b, acc[ct], 0, 0, 0);
        }
    }

    #pragma unroll
    for (int ct = 0; ct < 4; ++ct) {
        int col = ct * 16 + (lane & 15);
        #pragma unroll
        for (int reg = 0; reg < 4; ++reg) {
            int row = wv * 16 + (lane >> 4) * 4 + reg;
            if (row < nmax) {
                if (isroot)
                    agg1[(size_t)(n0 + row) * 64 + col] = acc[ct][reg] + b1[col];
                else
                    out[(size_t)(n0 + row) * 64 + col] = f2bf(acc[ct][reg]);
            }
        }
    }
}

// ---------------------------------------------------------------------------
// Layer-2 GEMMs (MFMA bf16), blockIdx.y in [0,9):
//   y<8 : h2[y][n][0:40] = y1b[n][0:64] @ W2_rel[y]     (bf16 out)
//   y==8: agg2[n][0:40] = y1b[n][0:64] @ W2_root + b2   (f32 out)
// ---------------------------------------------------------------------------
__global__ __launch_bounds__(256) void gemm2_mfma(
    const ushort* __restrict__ y1b, const ushort* __restrict__ w2t,
    ushort* __restrict__ hout, float* __restrict__ agg2,
    const float* __restrict__ b2, int nN)
{
    __shared__ ushort ys[64 * 64];
    __shared__ ushort wt[48 * 64];
    const int y    = blockIdx.y;
    const int tid  = threadIdx.x;
    const int n0   = blockIdx.x * 64;
    const int nmax = nN - n0;
    const bool isroot = (y == 8);
    ushort* out = hout + (size_t)y * nN * 40;
    const ushort* wsrc = w2t + (size_t)y * 48 * 64;

    for (int i = tid; i < 512; i += 256) {
        int row = i >> 3, ch = i & 7;
        uint4 v = make_uint4(0u, 0u, 0u, 0u);
        if (row < nmax)
            v = *(const uint4*)(y1b + (size_t)(n0 + row) * 64 + ch * 8);
        int off = (row * 128 + ch * 16) ^ ((row & 7) << 4);
        *(uint4*)((char*)ys + off) = v;
    }
    for (int i = tid; i < 384; i += 256) {
        int row = i >> 3, ch = i & 7;
        uint4 v = *(const uint4*)(wsrc + (size_t)row * 64 + ch * 8);
        int off = (row * 128 + ch * 16) ^ ((row & 7) << 4);
        *(uint4*)((char*)wt + off) = v;
    }
    __syncthreads();

    const int wv   = tid >> 6;
    const int lane = tid & 63;
    const int lr   = wv * 16 + (lane & 15);
    const int kgb  = (lane >> 4) * 8;

    f32x4 acc[3] = {{0.f,0.f,0.f,0.f},{0.f,0.f,0.f,0.f},{0.f,0.f,0.f,0.f}};

    #pragma unroll
    for (int ks = 0; ks < 2; ++ks) {
        int kb = (ks * 32 + kgb) * 2;
        int aoff = (lr * 128 + kb) ^ ((lr & 7) << 4);
        bf16x8 a = *(const bf16x8*)((const char*)ys + aoff);
        #pragma unroll
        for (int ct = 0; ct < 3; ++ct) {
            int col = ct * 16 + (lane & 15);
            int boff = (col * 128 + kb) ^ ((col & 7) << 4);
            bf16x8 b = *(const bf16x8*)((const char*)wt + boff);
            acc[ct] = __builtin_amdgcn_mfma_f32_16x16x32_bf16(a, b, acc[ct], 0, 0, 0);
        }
    }

    #pragma unroll
    for (int ct = 0; ct < 3; ++ct) {
        int col = ct * 16 + (lane & 15);
        if (col < 40) {
            #pragma unroll
            for (int reg = 0; reg < 4; ++reg) {
                int row = wv * 16 + (lane >> 4) * 4 + reg;
                if (row < nmax) {
                    if (isroot)
                        agg2[(size_t)(n0 + row) * 40 + col] = acc[ct][reg] + b2[col];
                    else
                        out[(size_t)(n0 + row) * 40 + col] = f2bf(acc[ct][reg]);
                }
            }
        }
    }
}

// ---------------------------------------------------------------------------
// CSR build part 1: per-node histogram -> 3-phase exclusive scan (row_off)
// ---------------------------------------------------------------------------
__global__ __launch_bounds__(256) void hist_dst(
    const int* __restrict__ dst, int* __restrict__ counts, int nE)
{
    int e = blockIdx.x * 256 + threadIdx.x;
    if (e < nE) atomicAdd(&counts[dst[e]], 1);
}

__global__ __launch_bounds__(256) void scan_partial(
    const int* __restrict__ counts, int* __restrict__ bsum, int nN)
{
    __shared__ int s[256];
    int t = threadIdx.x;
    int i = blockIdx.x * 256 + t;
    int v = (i < nN) ? counts[i] : 0;
    s[t] = v; __syncthreads();
    for (int o = 1; o < 256; o <<= 1) {
        int u = (t >= o) ? s[t - o] : 0;
        __syncthreads(); s[t] += u; __syncthreads();
    }
    if (t == 255) bsum[blockIdx.x] = s[255];
}

__global__ __launch_bounds__(512) void scan_base(
    const int* __restrict__ bsum, int* __restrict__ bbase, int nb,
    int* __restrict__ row_off, int nN)
{
    __shared__ int s[512];
    int t = threadIdx.x;
    int v = (t < nb) ? bsum[t] : 0;
    s[t] = v; __syncthreads();
    for (int o = 1; o < 512; o <<= 1) {
        int u = (t >= o) ? s[t - o] : 0;
        __syncthreads(); s[t] += u; __syncthreads();
    }
    if (t < nb) bbase[t] = s[t] - v;
    if (t == nb - 1) row_off[nN] = s[t];
}

__global__ __launch_bounds__(256) void scan_final(
    const int* __restrict__ counts, const int* __restrict__ bbase,
    int* __restrict__ row_off, int* __restrict__ cursor, int nN)
{
    __shared__ int s[256];
    int t = threadIdx.x;
    int i = blockIdx.x * 256 + t;
    int v = (i < nN) ? counts[i] : 0;
    s[t] = v; __syncthreads();
    for (int o = 1; o < 256; o <<= 1) {
        int u = (t >= o) ? s[t - o] : 0;
        __syncthreads(); s[t] += u; __syncthreads();
    }
    if (i < nN) {
        int off = bbase[blockIdx.x] + s[t] - v;
        row_off[i] = off;
        cursor[i]  = off;
    }
}

// ---------------------------------------------------------------------------
// CSR build part 2: deterministic two-stage multisplit.
// Stage 1 groups edges by 256-node bucket (391 buckets) with NO global
// atomics and coalesced writes; stage 2 sorts each 128-node half to exact
// per-node CSR order via LDS cursors, linear flush.
// payload pk: bits 0..16 src, 20..22 color, 23..30 dst&255
// ---------------------------------------------------------------------------
__global__ __launch_bounds__(256) void mcount(
    const int* __restrict__ dst, int* __restrict__ cnt, int nE, int nBkt)
{
    __shared__ int hist[512];
    const int blk = blockIdx.x;
    const int t = threadIdx.x;
    for (int i = t; i < nBkt; i += 256) hist[i] = 0;
    __syncthreads();
    const int e0 = blk * CH;
    const int eend = min(e0 + CH, nE);
    for (int e = e0 + t; e < eend; e += 256)
        atomicAdd(&hist[dst[e] >> 8], 1);
    __syncthreads();
    for (int i = t; i < nBkt; i += 256)
        cnt[(size_t)blk * nBkt + i] = hist[i];
}

// one block per bucket: off[bkt][blk] = row_off[bkt*256] + sum_{b<blk} cnt[b][bkt]
__global__ __launch_bounds__(1024) void scanB(
    const int* __restrict__ cnt, const int* __restrict__ row_off,
    int* __restrict__ off, int nBlk, int nBkt, int nN)
{
    __shared__ int s[1024];
    const int bkt = blockIdx.x;
    const int t = threadIdx.x;
    int v = (t < nBlk) ? cnt[(size_t)t * nBkt + bkt] : 0;
    s[t] = v; __syncthreads();
    for (int o = 1; o < 1024; o <<= 1) {
        int u = (t >= o) ? s[t - o] : 0;
        __syncthreads(); s[t] += u; __syncthreads();
    }
    if (t < nBlk)
        off[(size_t)bkt * nBlk + t] = row_off[min(bkt << 8, nN)] + s[t] - v;
}

__global__ __launch_bounds__(512) void mscatter(
    const int* __restrict__ src, const int* __restrict__ dst,
    const float* __restrict__ ew, const int* __restrict__ ec,
    const int* __restrict__ cnt, const int* __restrict__ off,
    uint2* __restrict__ epackA, int nE, int nBlk, int nBkt)
{
    __shared__ uint2 stag[CH];
    __shared__ int lbase[512];
    __shared__ int lcur[512];
    __shared__ int goff[512];
    const int blk = blockIdx.x;
    const int t = threadIdx.x;

    int v = (t < nBkt) ? cnt[(size_t)blk * nBkt + t] : 0;
    lbase[t] = v; __syncthreads();
    for (int o = 1; o < 512; o <<= 1) {
        int u = (t >= o) ? lbase[t - o] : 0;
        __syncthreads(); lbase[t] += u; __syncthreads();
    }
    int excl = lbase[t] - v;
    __syncthreads();
    lbase[t] = excl;
    lcur[t] = excl;
    goff[t] = (t < nBkt) ? off[(size_t)t * nBlk + blk] : 0;
    __syncthreads();

    const int e0 = blk * CH;
    const int eend = min(e0 + CH, nE);
    const int ntot = eend - e0;
    for (int e = e0 + t; e < eend; e += 512) {
        int d = dst[e];
        int bkt = d >> 8;
        unsigned int pk = (unsigned int)src[e] | ((unsigned int)ec[e] << 20)
                        | ((unsigned int)(d & 255) << 23);
        int r = atomicAdd(&lcur[bkt], 1);
        stag[r] = make_uint2(pk, __float_as_uint(ew[e]));
    }
    __syncthreads();
    // flush: consecutive slots -> contiguous global runs (coalesced writes)
    for (int s2 = t; s2 < ntot; s2 += 512) {
        int lo = 0, hi = nBkt - 1;
        while (lo < hi) {
            int mid = (lo + hi + 1) >> 1;
            if (lbase[mid] <= s2) lo = mid; else hi = mid - 1;
        }
        epackA[goff[lo] + (s2 - lbase[lo])] = stag[s2];
    }
}

// stage 2: one block per 128 nodes; parent segment is the 256-node bucket.
__global__ __launch_bounds__(256) void reorder2(
    const uint2* __restrict__ epackA, const int* __restrict__ row_off,
    int* __restrict__ gcur, uint2* __restrict__ epack, int nN)
{
    __shared__ uint2 stag[ST2CAP];
    __shared__ int lcur[128];
    const int b  = blockIdx.x;
    const int n0 = b << 7;
    const int pb = b >> 1;
    const int p0 = row_off[min(pb << 8, nN)];
    const int p1 = row_off[min((pb + 1) << 8, nN)];
    const int s0 = row_off[n0];
    const int s1 = row_off[min(n0 + 128, nN)];
    const int half = (n0 >> 7) & 1;
    const int t = threadIdx.x;
    const int ne = s1 - s0;
    if (t < 128) {
        int idx = n0 + t;
        lcur[t] = (idx < nN) ? (row_off[idx] - s0) : ne;
    }
    __syncthreads();
    if (ne <= ST2CAP) {
        for (int e = p0 + t; e < p1; e += 256) {
            uint2 pw = epackA[e];
            int dl = (pw.x >> 23) & 255;
            if ((dl >> 7) == half) {
                int r = atomicAdd(&lcur[dl & 127], 1);
                stag[r] = pw;
            }
        }
        __syncthreads();
        for (int s2 = t; s2 < ne; s2 += 256)
            epack[s0 + s2] = stag[s2];
    } else {
        // never expected for uniform dst; correctness fallback
        for (int e = p0 + t; e < p1; e += 256) {
            uint2 pw = epackA[e];
            int dl = (pw.x >> 23) & 255;
            if ((dl >> 7) == half) {
                int p = atomicAdd(&gcur[n0 + (dl & 127)], 1);
                epack[p] = pw;
            }
        }
    }
}

// ws-too-small / odd-shape fallback: direct scatter fill (round-5 path)
__global__ __launch_bounds__(256) void fill_csr(
    const int* __restrict__ src, const int* __restrict__ dst,
    const float* __restrict__ ew, const int* __restrict__ ec,
    int* __restrict__ cursor, uint2* __restrict__ epack, int nE)
{
    int e = blockIdx.x * 256 + threadIdx.x;
    if (e >= nE) return;
    int p = atomicAdd(&cursor[dst[e]], 1);
    epack[p] = make_uint2((unsigned int)src[e] | ((unsigned int)ec[e] << 20),
                          __float_as_uint(ew[e]));
}

// ---------------------------------------------------------------------------
// Gather aggregation, DIMS=64: one wave per dst node, lane = dim.
// 8-wide software pipeline: 8 independent loads in flight per wave.
// ---------------------------------------------------------------------------
__global__ __launch_bounds__(256) void gather_d64(
    const ushort* __restrict__ h, const int* __restrict__ row_off,
    const uint2* __restrict__ epack, float* __restrict__ agg, int nN)
{
    int w    = (blockIdx.x * 256 + threadIdx.x) >> 6;
    int lane = threadIdx.x & 63;
    if (w >= nN) return;
    int s0 = row_off[w], s1 = row_off[w + 1];
    float acc = agg[(size_t)w * 64 + lane];
    const unsigned int un = (unsigned int)nN;
    for (int base = s0; base < s1; base += 64) {
        int m = min(64, s1 - base);
        unsigned int pk = 0; float wv = 0.f;
        if (lane < m) {
            uint2 pw = epack[base + lane];
            pk = pw.x; wv = __uint_as_float(pw.y);
        }
        int j = 0;
        for (; j + 8 <= m; j += 8) {
            unsigned int p0 = __shfl(pk, j + 0, 64), p1 = __shfl(pk, j + 1, 64);
            unsigned int p2 = __shfl(pk, j + 2, 64), p3 = __shfl(pk, j + 3, 64);
            unsigned int p4 = __shfl(pk, j + 4, 64), p5 = __shfl(pk, j + 5, 64);
            unsigned int p6 = __shfl(pk, j + 6, 64), p7 = __shfl(pk, j + 7, 64);
            float q0 = __shfl(wv, j + 0, 64), q1 = __shfl(wv, j + 1, 64);
            float q2 = __shfl(wv, j + 2, 64), q3 = __shfl(wv, j + 3, 64);
            float q4 = __shfl(wv, j + 4, 64), q5 = __shfl(wv, j + 5, 64);
            float q6 = __shfl(wv, j + 6, 64), q7 = __shfl(wv, j + 7, 64);
            ushort v0 = h[(((p0 >> 20) & 7) * un + (p0 & 0xFFFFFu)) * 64u + lane];
            ushort v1 = h[(((p1 >> 20) & 7) * un + (p1 & 0xFFFFFu)) * 64u + lane];
            ushort v2 = h[(((p2 >> 20) & 7) * un + (p2 & 0xFFFFFu)) * 64u + lane];
            ushort v3 = h[(((p3 >> 20) & 7) * un + (p3 & 0xFFFFFu)) * 64u + lane];
            ushort v4 = h[(((p4 >> 20) & 7) * un + (p4 & 0xFFFFFu)) * 64u + lane];
            ushort v5 = h[(((p5 >> 20) & 7) * un + (p5 & 0xFFFFFu)) * 64u + lane];
            ushort v6 = h[(((p6 >> 20) & 7) * un + (p6 & 0xFFFFFu)) * 64u + lane];
            ushort v7 = h[(((p7 >> 20) & 7) * un + (p7 & 0xFFFFFu)) * 64u + lane];
            acc = fmaf(q0, bf2f(v0), acc); acc = fmaf(q1, bf2f(v1), acc);
            acc = fmaf(q2, bf2f(v2), acc); acc = fmaf(q3, bf2f(v3), acc);
            acc = fmaf(q4, bf2f(v4), acc); acc = fmaf(q5, bf2f(v5), acc);
            acc = fmaf(q6, bf2f(v6), acc); acc = fmaf(q7, bf2f(v7), acc);
        }
        for (; j < m; ++j) {
            unsigned int pj = __shfl(pk, j, 64);
            float        wj = __shfl(wv, j, 64);
            ushort v = h[(((pj >> 20) & 7) * un + (pj & 0xFFFFFu)) * 64u + lane];
            acc = fmaf(wj, bf2f(v), acc);
        }
    }
    agg[(size_t)w * 64 + lane] = acc;
}

// ---------------------------------------------------------------------------
// Gather aggregation, C=40: lanes 0..39 accumulate; same 8-wide pipeline.
// ---------------------------------------------------------------------------
__global__ __launch_bounds__(256) void gather_d40(
    const ushort* __restrict__ h, const int* __restrict__ row_off,
    const uint2* __restrict__ epack, float* __restrict__ agg, int nN)
{
    int w    = (blockIdx.x * 256 + threadIdx.x) >> 6;
    int lane = threadIdx.x & 63;
    if (w >= nN) return;
    int s0 = row_off[w], s1 = row_off[w + 1];
    float acc = 0.f;
    if (lane < 40) acc = agg[(size_t)w * 40 + lane];
    const unsigned int un = (unsigned int)nN;
    for (int base = s0; base < s1; base += 64) {
        int m = min(64, s1 - base);
        unsigned int pk = 0; float wv = 0.f;
        if (lane < m) {
            uint2 pw = epack[base + lane];
            pk = pw.x; wv = __uint_as_float(pw.y);
        }
        int j = 0;
        for (; j + 8 <= m; j += 8) {
            unsigned int p0 = __shfl(pk, j + 0, 64), p1 = __shfl(pk, j + 1, 64);
            unsigned int p2 = __shfl(pk, j + 2, 64), p3 = __shfl(pk, j + 3, 64);
            unsigned int p4 = __shfl(pk, j + 4, 64), p5 = __shfl(pk, j + 5, 64);
            unsigned int p6 = __shfl(pk, j + 6, 64), p7 = __shfl(pk, j + 7, 64);
            float q0 = __shfl(wv, j + 0, 64), q1 = __shfl(wv, j + 1, 64);
            float q2 = __shfl(wv, j + 2, 64), q3 = __shfl(wv, j + 3, 64);
            float q4 = __shfl(wv, j + 4, 64), q5 = __shfl(wv, j + 5, 64);
            float q6 = __shfl(wv, j + 6, 64), q7 = __shfl(wv, j + 7, 64);
            if (lane < 40) {
                ushort v0 = h[(((p0 >> 20) & 7) * un + (p0 & 0xFFFFFu)) * 40u + lane];
                ushort v1 = h[(((p1 >> 20) & 7) * un + (p1 & 0xFFFFFu)) * 40u + lane];
                ushort v2 = h[(((p2 >> 20) & 7) * un + (p2 & 0xFFFFFu)) * 40u + lane];
                ushort v3 = h[(((p3 >> 20) & 7) * un + (p3 & 0xFFFFFu)) * 40u + lane];
                ushort v4 = h[(((p4 >> 20) & 7) * un + (p4 & 0xFFFFFu)) * 40u + lane];
                ushort v5 = h[(((p5 >> 20) & 7) * un + (p5 & 0xFFFFFu)) * 40u + lane];
                ushort v6 = h[(((p6 >> 20) & 7) * un + (p6 & 0xFFFFFu)) * 40u + lane];
                ushort v7 = h[(((p7 >> 20) & 7) * un + (p7 & 0xFFFFFu)) * 40u + lane];
                acc = fmaf(q0, bf2f(v0), acc); acc = fmaf(q1, bf2f(v1), acc);
                acc = fmaf(q2, bf2f(v2), acc); acc = fmaf(q3, bf2f(v3), acc);
                acc = fmaf(q4, bf2f(v4), acc); acc = fmaf(q5, bf2f(v5), acc);
                acc = fmaf(q6, bf2f(v6), acc); acc = fmaf(q7, bf2f(v7), acc);
            }
        }
        for (; j < m; ++j) {
            unsigned int pj = __shfl(pk, j, 64);
            float        wj = __shfl(wv, j, 64);
            if (lane < 40) {
                ushort v = h[(((pj >> 20) & 7) * un + (pj & 0xFFFFFu)) * 40u + lane];
                acc = fmaf(wj, bf2f(v), acc);
            }
        }
    }
    if (lane < 40) agg[(size_t)w * 40 + lane] = acc;
}

// ---------------------------------------------------------------------------
// Epilogue: (log_softmax(out), out)
// ---------------------------------------------------------------------------
__global__ __launch_bounds__(256) void logsoftmax_out(
    const float* __restrict__ agg2, float* __restrict__ out, int nN)
{
    int w    = (blockIdx.x * 256 + threadIdx.x) >> 6;
    int lane = threadIdx.x & 63;
    if (w >= nN) return;
    float v = -INFINITY;
    if (lane < 40) v = agg2[(size_t)w * 40 + lane];
    float m = v;
    #pragma unroll
    for (int o = 32; o > 0; o >>= 1) m = fmaxf(m, __shfl_xor(m, o, 64));
    float ex = (lane < 40) ? expf(v - m) : 0.f;
    float s = ex;
    #pragma unroll
    for (int o = 32; o > 0; o >>= 1) s += __shfl_xor(s, o, 64);
    float lse = logf(s) + m;
    if (lane < 40) {
        out[(size_t)w * 40 + lane] = v - lse;
        out[(size_t)nN * 40 + (size_t)w * 40 + lane] = v;
    }
}

// ---------------------------------------------------------------------------
extern "C" void kernel_launch(void* const* d_in, const int* in_sizes, int n_in,
                              void* d_out, int out_size, void* d_ws, size_t ws_size,
                              hipStream_t stream)
{
    const float* x       = (const float*)d_in[0];
    const int*   eidx    = (const int*)  d_in[1];
    const float* ew      = (const float*)d_in[2];
    const int*   ec      = (const int*)  d_in[3];
    const float* W1_rel  = (const float*)d_in[4];
    const float* W1_root = (const float*)d_in[5];
    const float* b1      = (const float*)d_in[6];
    const float* W2_rel  = (const float*)d_in[7];
    const float* W2_root = (const float*)d_in[8];
    const float* b2      = (const float*)d_in[9];

    const int nN = in_sizes[0] / 128;   // 100000
    const int nE = in_sizes[2];         // 3200000
    const int* src = eidx;
    const int* dst = eidx + nE;

    const int nBkt = (nN + 255) >> 8;          // 391 stage-1 buckets
    const int nBlk = (nE + CH - 1) / CH;       // 782 multisplit chunks

    char* w8 = (char*)d_ws;
    size_t off = 0;
    auto alloc = [&](size_t bytes) {
        void* p = w8 + off;
        off += (bytes + 255) & ~(size_t)255;
        return p;
    };
    ushort* h      = (ushort*)alloc((size_t)RELS * nN * 64 * 2);
    ushort* xb     = (ushort*)alloc((size_t)nN * 128 * 2);
    float*  agg1   = (float*) alloc((size_t)nN * 64 * 4);
    float*  agg2   = (float*) alloc((size_t)nN * 40 * 4);
    int*    counts = (int*)   alloc((size_t)nN * 4);
    int*    row_off= (int*)   alloc(((size_t)nN + 1) * 4);
    int*    cursor = (int*)   alloc((size_t)nN * 4);
    int*    bsum   = (int*)   alloc(4096);
    int*    bbase  = (int*)   alloc(4096);
    uint2*  epack  = (uint2*) alloc((size_t)nE * 8);
    ushort* w1t    = (ushort*)alloc((size_t)9 * 64 * 128 * 2);
    ushort* w2t    = (ushort*)alloc((size_t)9 * 48 * 64 * 2);
    size_t  base_need = off;
    int*    cnt    = (int*)   alloc((size_t)nBlk * nBkt * 4);
    int*    offm   = (int*)   alloc((size_t)nBkt * nBlk * 4);
    uint2*  epackA = (uint2*) alloc((size_t)nE * 8);
    const bool multisplit = (off <= ws_size) && (nBlk <= 1024) && (nBkt <= 512);
    ushort* y1b = xb;   // x bf16 dead after layer-1 GEMMs
    (void)base_need;

    const dim3 blk(256);
    const int NB_scan     = (nN + 255) / 256;
    const int gemm_blocks = (nN + 63) / 64;
    const int edge_blocks = (nE + 255) / 256;
    const int wave_blocks = (int)(((size_t)nN * 64 + 255) / 256);
    const int ls_blocks   = (nN + 3) / 4;

    // ---- CSR build: histogram + node scan
    hipMemsetAsync(counts, 0, (size_t)nN * 4, stream);
    hist_dst<<<edge_blocks, blk, 0, stream>>>(dst, counts, nE);
    scan_partial<<<NB_scan, blk, 0, stream>>>(counts, bsum, nN);
    scan_base<<<1, dim3(512), 0, stream>>>(bsum, bbase, NB_scan, row_off, nN);
    scan_final<<<NB_scan, blk, 0, stream>>>(counts, bbase, row_off, cursor, nN);

    if (multisplit) {
        mcount<<<nBlk, blk, 0, stream>>>(dst, cnt, nE, nBkt);
        scanB<<<nBkt, dim3(1024), 0, stream>>>(cnt, row_off, offm, nBlk, nBkt, nN);
        mscatter<<<nBlk, dim3(512), 0, stream>>>(src, dst, ew, ec, cnt, offm,
                                                 epackA, nE, nBlk, nBkt);
        reorder2<<<(nN + 127) / 128, blk, 0, stream>>>(epackA, row_off, cursor,
                                                       epack, nN);
    } else {
        fill_csr<<<edge_blocks, blk, 0, stream>>>(src, dst, ew, ec, cursor, epack, nE);
    }

    // ---- weight/input prep (bf16)
    cast_f32_bf16x4<<<(nN * 128 / 4 + 255) / 256, blk, 0, stream>>>(x, xb, nN * 128 / 4);
    conv_w1<<<(9 * 64 * 128 + 255) / 256, blk, 0, stream>>>(W1_rel, W1_root, w1t);
    conv_w2<<<(9 * 48 * 64 + 255) / 256, blk, 0, stream>>>(W2_rel, W2_root, w2t);

    // ---- Layer 1
    gemm1_mfma<<<dim3(gemm_blocks, 9), blk, 0, stream>>>(xb, w1t, h, agg1, b1, nN);
    gather_d64<<<wave_blocks, blk, 0, stream>>>(h, row_off, epack, agg1, nN);

    // ---- Layer 2
    cast_relu_bf16x4<<<(nN * 64 / 4 + 255) / 256, blk, 0, stream>>>(agg1, y1b, nN * 64 / 4);
    gemm2_mfma<<<dim3(gemm_blocks, 9), blk, 0, stream>>>(y1b, w2t, h, agg2, b2, nN);
    gather_d40<<<wave_blocks, blk, 0, stream>>>(h, row_off, epack, agg2, nN);

    // ---- Epilogue
    logsoftmax_out<<<ls_blocks, blk, 0, stream>>>(agg2, (float*)d_out, nN);
}

// Round 7
// 419.728 us; speedup vs baseline: 2.9576x; 1.2934x over previous
//
#include <hip/hip_runtime.h>
#include <hip/hip_bf16.h>
#include <cmath>

// WRGCN: 2-layer weighted relational GCN.
// N=100000, E=3200000, R=8, F_IN=128, DIMS=64, C=40.
// Lessons encoded here:
//  - scattered partial-line stores/atomics cost a full 64B line each,
//    regardless of temporal locality (r4/r5/r6 counters) -> all edge-rate
//    memory ops must be LDS-staged and flushed linearly.
//  - never funnel E atomics into few cursors (r4: 782 cursors -> 749us chain).
//  - r6: even the per-node histogram (3.2M atomics over 400KB) cost 129us;
//    now derived from the multisplit's own bucket counts, zero global atomics
//    in the entire CSR build.
// 8-wide-pipelined gathers; all GEMMs (incl. root) on bf16 MFMA.

#define RELS 8
#define CH 4096       // edges per multisplit chunk
#define ST2CAP 6144   // stage-2 LDS staging capacity (mean 4096)

typedef __attribute__((ext_vector_type(8))) short bf16x8;
typedef __attribute__((ext_vector_type(4))) float f32x4;

static __device__ __forceinline__ ushort f2bf(float f) {
    __hip_bfloat16 b = __float2bfloat16(f);
    return *reinterpret_cast<ushort*>(&b);
}
static __device__ __forceinline__ float bf2f(ushort u) {
    return __uint_as_float(((unsigned int)u) << 16);
}

// ---------------------------------------------------------------------------
// Casts / weight prep
// ---------------------------------------------------------------------------
__global__ __launch_bounds__(256) void cast_f32_bf16x4(
    const float* __restrict__ in, ushort* __restrict__ out, int n4)
{
    int i = blockIdx.x * 256 + threadIdx.x;
    if (i >= n4) return;
    float4 v = ((const float4*)in)[i];
    ushort4 o;
    o.x = f2bf(v.x); o.y = f2bf(v.y); o.z = f2bf(v.z); o.w = f2bf(v.w);
    ((ushort4*)out)[i] = o;
}

__global__ __launch_bounds__(256) void cast_relu_bf16x4(
    const float* __restrict__ in, ushort* __restrict__ out, int n4)
{
    int i = blockIdx.x * 256 + threadIdx.x;
    if (i >= n4) return;
    float4 v = ((const float4*)in)[i];
    ushort4 o;
    o.x = f2bf(fmaxf(v.x, 0.f)); o.y = f2bf(fmaxf(v.y, 0.f));
    o.z = f2bf(fmaxf(v.z, 0.f)); o.w = f2bf(fmaxf(v.w, 0.f));
    ((ushort4*)out)[i] = o;
}

// w1t[r][c][k]: r in [0,9): r<8 from W1_rel [R][128][64]; r==8 from W1_root.
__global__ __launch_bounds__(256) void conv_w1(
    const float* __restrict__ Wrel, const float* __restrict__ Wroot,
    ushort* __restrict__ wt)
{
    int i = blockIdx.x * 256 + threadIdx.x;
    if (i >= 9 * 64 * 128) return;
    int r = i >> 13, c = (i >> 7) & 63, k = i & 127;
    float v = (r < 8) ? Wrel[((size_t)r * 128 + k) * 64 + c]
                      : Wroot[(size_t)k * 64 + c];
    wt[i] = f2bf(v);
}

// w2t[r][c][k]: r in [0,9), c in [0,48) (pad 40..47 = 0), k in [0,64).
__global__ __launch_bounds__(256) void conv_w2(
    const float* __restrict__ Wrel, const float* __restrict__ Wroot,
    ushort* __restrict__ wt)
{
    int i = blockIdx.x * 256 + threadIdx.x;
    if (i >= 9 * 48 * 64) return;
    int r = i / (48 * 64), rem = i - r * (48 * 64);
    int c = rem >> 6, k = rem & 63;
    float v = 0.f;
    if (c < 40)
        v = (r < 8) ? Wrel[((size_t)r * 64 + k) * 40 + c]
                    : Wroot[(size_t)k * 40 + c];
    wt[i] = f2bf(v);
}

// ---------------------------------------------------------------------------
// Layer-1 GEMMs (MFMA bf16), blockIdx.y in [0,9):
//   y<8 : h[y][n][0:64] = xb[n][0:128] @ W1_rel[y]      (bf16 out)
//   y==8: agg1[n][0:64] = xb[n][0:128] @ W1_root + b1   (f32 out)
// ---------------------------------------------------------------------------
__global__ __launch_bounds__(256) void gemm1_mfma(
    const ushort* __restrict__ xb, const ushort* __restrict__ w1t,
    ushort* __restrict__ hout, float* __restrict__ agg1,
    const float* __restrict__ b1, int nN)
{
    __shared__ ushort xs[64 * 128];
    __shared__ ushort wt[64 * 128];
    const int y    = blockIdx.y;
    const int tid  = threadIdx.x;
    const int n0   = blockIdx.x * 64;
    const int nmax = nN - n0;
    const bool isroot = (y == 8);
    ushort* out = hout + (size_t)y * nN * 64;
    const ushort* wsrc = w1t + (size_t)y * 64 * 128;

    for (int i = tid; i < 1024; i += 256) {
        int row = i >> 4, ch = i & 15;
        uint4 v = make_uint4(0u, 0u, 0u, 0u);
        if (row < nmax)
            v = *(const uint4*)(xb + (size_t)(n0 + row) * 128 + ch * 8);
        int off = (row * 256 + ch * 16) ^ ((row & 7) << 4);
        *(uint4*)((char*)xs + off) = v;
    }
    for (int i = tid; i < 1024; i += 256) {
        int row = i >> 4, ch = i & 15;
        uint4 v = *(const uint4*)(wsrc + (size_t)row * 128 + ch * 8);
        int off = (row * 256 + ch * 16) ^ ((row & 7) << 4);
        *(uint4*)((char*)wt + off) = v;
    }
    __syncthreads();

    const int wv   = tid >> 6;
    const int lane = tid & 63;
    const int lr   = wv * 16 + (lane & 15);
    const int kgb  = (lane >> 4) * 8;

    f32x4 acc[4] = {{0.f,0.f,0.f,0.f},{0.f,0.f,0.f,0.f},
                    {0.f,0.f,0.f,0.f},{0.f,0.f,0.f,0.f}};

    #pragma unroll
    for (int ks = 0; ks < 4; ++ks) {
        int kb = (ks * 32 + kgb) * 2;
        int aoff = (lr * 256 + kb) ^ ((lr & 7) << 4);
        bf16x8 a = *(const bf16x8*)((const char*)xs + aoff);
        #pragma unroll
        for (int ct = 0; ct < 4; ++ct) {
            int col = ct * 16 + (lane & 15);
            int boff = (col * 256 + kb) ^ ((col & 7) << 4);
            bf16x8 b = *(const bf16x8*)((const char*)wt + boff);
            acc[ct] = __builtin_amdgcn_mfma_f32_16x16x32_bf16(a, b, acc[ct], 0, 0, 0);
        }
    }

    #pragma unroll
    for (int ct = 0; ct < 4; ++ct) {
        int col = ct * 16 + (lane & 15);
        #pragma unroll
        for (int reg = 0; reg < 4; ++reg) {
            int row = wv * 16 + (lane >> 4) * 4 + reg;
            if (row < nmax) {
                if (isroot)
                    agg1[(size_t)(n0 + row) * 64 + col] = acc[ct][reg] + b1[col];
                else
                    out[(size_t)(n0 + row) * 64 + col] = f2bf(acc[ct][reg]);
            }
        }
    }
}

// ---------------------------------------------------------------------------
// Layer-2 GEMMs (MFMA bf16), blockIdx.y in [0,9):
//   y<8 : h2[y][n][0:40] = y1b[n][0:64] @ W2_rel[y]     (bf16 out)
//   y==8: agg2[n][0:40] = y1b[n][0:64] @ W2_root + b2   (f32 out)
// ---------------------------------------------------------------------------
__global__ __launch_bounds__(256) void gemm2_mfma(
    const ushort* __restrict__ y1b, const ushort* __restrict__ w2t,
    ushort* __restrict__ hout, float* __restrict__ agg2,
    const float* __restrict__ b2, int nN)
{
    __shared__ ushort ys[64 * 64];
    __shared__ ushort wt[48 * 64];
    const int y    = blockIdx.y;
    const int tid  = threadIdx.x;
    const int n0   = blockIdx.x * 64;
    const int nmax = nN - n0;
    const bool isroot = (y == 8);
    ushort* out = hout + (size_t)y * nN * 40;
    const ushort* wsrc = w2t + (size_t)y * 48 * 64;

    for (int i = tid; i < 512; i += 256) {
        int row = i >> 3, ch = i & 7;
        uint4 v = make_uint4(0u, 0u, 0u, 0u);
        if (row < nmax)
            v = *(const uint4*)(y1b + (size_t)(n0 + row) * 64 + ch * 8);
        int off = (row * 128 + ch * 16) ^ ((row & 7) << 4);
        *(uint4*)((char*)ys + off) = v;
    }
    for (int i = tid; i < 384; i += 256) {
        int row = i >> 3, ch = i & 7;
        uint4 v = *(const uint4*)(wsrc + (size_t)row * 64 + ch * 8);
        int off = (row * 128 + ch * 16) ^ ((row & 7) << 4);
        *(uint4*)((char*)wt + off) = v;
    }
    __syncthreads();

    const int wv   = tid >> 6;
    const int lane = tid & 63;
    const int lr   = wv * 16 + (lane & 15);
    const int kgb  = (lane >> 4) * 8;

    f32x4 acc[3] = {{0.f,0.f,0.f,0.f},{0.f,0.f,0.f,0.f},{0.f,0.f,0.f,0.f}};

    #pragma unroll
    for (int ks = 0; ks < 2; ++ks) {
        int kb = (ks * 32 + kgb) * 2;
        int aoff = (lr * 128 + kb) ^ ((lr & 7) << 4);
        bf16x8 a = *(const bf16x8*)((const char*)ys + aoff);
        #pragma unroll
        for (int ct = 0; ct < 3; ++ct) {
            int col = ct * 16 + (lane & 15);
            int boff = (col * 128 + kb) ^ ((col & 7) << 4);
            bf16x8 b = *(const bf16x8*)((const char*)wt + boff);
            acc[ct] = __builtin_amdgcn_mfma_f32_16x16x32_bf16(a, b, acc[ct], 0, 0, 0);
        }
    }

    #pragma unroll
    for (int ct = 0; ct < 3; ++ct) {
        int col = ct * 16 + (lane & 15);
        if (col < 40) {
            #pragma unroll
            for (int reg = 0; reg < 4; ++reg) {
                int row = wv * 16 + (lane >> 4) * 4 + reg;
                if (row < nmax) {
                    if (isroot)
                        agg2[(size_t)(n0 + row) * 40 + col] = acc[ct][reg] + b2[col];
                    else
                        out[(size_t)(n0 + row) * 40 + col] = f2bf(acc[ct][reg]);
                }
            }
        }
    }
}

// ---------------------------------------------------------------------------
// CSR build: two-stage multisplit, zero global atomics.
// payload pk: bits 0..19 src, 20..22 color, 23..30 dst&255
// ---------------------------------------------------------------------------
__global__ __launch_bounds__(256) void mcount(
    const int* __restrict__ dst, int* __restrict__ cnt, int nE, int nBkt)
{
    __shared__ int hist[512];
    const int blk = blockIdx.x;
    const int t = threadIdx.x;
    for (int i = t; i < nBkt; i += 256) hist[i] = 0;
    __syncthreads();
    const int e0 = blk * CH;
    const int eend = min(e0 + CH, nE);
    for (int e = e0 + t; e < eend; e += 256)
        atomicAdd(&hist[dst[e] >> 8], 1);
    __syncthreads();
    for (int i = t; i < nBkt; i += 256)
        cnt[(size_t)blk * nBkt + i] = hist[i];
}

// per bucket: scan over chunks -> relative offsets + bucket total
__global__ __launch_bounds__(1024) void scanB(
    const int* __restrict__ cnt, int* __restrict__ offm_rel,
    int* __restrict__ tsum, int nBlk, int nBkt)
{
    __shared__ int s[1024];
    const int bkt = blockIdx.x;
    const int t = threadIdx.x;
    int v = (t < nBlk) ? cnt[(size_t)t * nBkt + bkt] : 0;
    s[t] = v; __syncthreads();
    for (int o = 1; o < 1024; o <<= 1) {
        int u = (t >= o) ? s[t - o] : 0;
        __syncthreads(); s[t] += u; __syncthreads();
    }
    if (t < nBlk) offm_rel[(size_t)bkt * nBlk + t] = s[t] - v;
    if (t == nBlk - 1) tsum[bkt] = s[t];
}

// single block: exclusive scan of bucket totals -> bucket bases; row_off[nN]=E
__global__ __launch_bounds__(512) void scanT(
    const int* __restrict__ tsum, int* __restrict__ bktbase,
    int* __restrict__ row_off, int nBkt, int nN)
{
    __shared__ int s[512];
    const int t = threadIdx.x;
    int v = (t < nBkt) ? tsum[t] : 0;
    s[t] = v; __syncthreads();
    for (int o = 1; o < 512; o <<= 1) {
        int u = (t >= o) ? s[t - o] : 0;
        __syncthreads(); s[t] += u; __syncthreads();
    }
    if (t < nBkt) bktbase[t] = s[t] - v;
    if (t == nBkt - 1) { bktbase[nBkt] = s[t]; row_off[nN] = s[t]; }
}

__global__ __launch_bounds__(512) void mscatter(
    const int* __restrict__ src, const int* __restrict__ dst,
    const float* __restrict__ ew, const int* __restrict__ ec,
    const int* __restrict__ cnt, const int* __restrict__ offm_rel,
    const int* __restrict__ bktbase,
    uint2* __restrict__ epackA, int nE, int nBlk, int nBkt)
{
    __shared__ uint2 stag[CH];
    __shared__ int lbase[512];
    __shared__ int lcur[512];
    __shared__ int goff[512];
    const int blk = blockIdx.x;
    const int t = threadIdx.x;

    int v = (t < nBkt) ? cnt[(size_t)blk * nBkt + t] : 0;
    lbase[t] = v; __syncthreads();
    for (int o = 1; o < 512; o <<= 1) {
        int u = (t >= o) ? lbase[t - o] : 0;
        __syncthreads(); lbase[t] += u; __syncthreads();
    }
    int excl = lbase[t] - v;
    __syncthreads();
    lbase[t] = excl;
    lcur[t] = excl;
    goff[t] = (t < nBkt) ? bktbase[t] + offm_rel[(size_t)t * nBlk + blk] : 0;
    __syncthreads();

    const int e0 = blk * CH;
    const int eend = min(e0 + CH, nE);
    const int ntot = eend - e0;
    for (int e = e0 + t; e < eend; e += 512) {
        int d = dst[e];
        int bkt = d >> 8;
        unsigned int pk = (unsigned int)src[e] | ((unsigned int)ec[e] << 20)
                        | ((unsigned int)(d & 255) << 23);
        int r = atomicAdd(&lcur[bkt], 1);
        stag[r] = make_uint2(pk, __float_as_uint(ew[e]));
    }
    __syncthreads();
    // flush: consecutive slots -> contiguous global runs (coalesced writes)
    for (int s2 = t; s2 < ntot; s2 += 512) {
        int lo = 0, hi = nBkt - 1;
        while (lo < hi) {
            int mid = (lo + hi + 1) >> 1;
            if (lbase[mid] <= s2) lo = mid; else hi = mid - 1;
        }
        epackA[goff[lo] + (s2 - lbase[lo])] = stag[s2];
    }
}

// stage 2: one block per 128-node half of a 256-node bucket.
// pass 1: LDS histogram of local dst + scan -> per-node offsets; WRITES row_off
// pass 2: LDS counting-sort of this half's edges, linear flush to epack.
__global__ __launch_bounds__(256) void reorder2(
    const uint2* __restrict__ epackA, const int* __restrict__ bktbase,
    int* __restrict__ row_off, uint2* __restrict__ epack, int nN)
{
    __shared__ uint2 stag[ST2CAP];
    __shared__ int hist[256];
    __shared__ int s[256];
    __shared__ int lcur[128];
    const int b    = blockIdx.x;
    const int n0   = b << 7;
    const int pb   = b >> 1;
    const int half = b & 1;
    const int p0 = bktbase[pb];
    const int p1 = bktbase[pb + 1];
    const int t = threadIdx.x;

    hist[t] = 0;
    __syncthreads();
    const unsigned int* ax = (const unsigned int*)epackA;
    for (int e = p0 + t; e < p1; e += 256)
        atomicAdd(&hist[(ax[2 * (size_t)e] >> 23) & 255], 1);
    __syncthreads();
    int v = hist[t];
    s[t] = v; __syncthreads();
    for (int o = 1; o < 256; o <<= 1) {
        int u = (t >= o) ? s[t - o] : 0;
        __syncthreads(); s[t] += u; __syncthreads();
    }
    hist[t] = s[t] - v;   // exclusive offsets within bucket
    __syncthreads();

    const int hb0 = hist[half << 7];
    const int hb1 = (half == 0) ? hist[128] : (p1 - p0);
    const int ne  = hb1 - hb0;
    const int s0  = p0 + hb0;

    if (t < 128) {
        int idx = n0 + t;
        if (idx < nN) row_off[idx] = p0 + hist[(half << 7) + t];
        lcur[t] = hist[(half << 7) + t] - hb0;
    }
    __syncthreads();

    if (ne <= ST2CAP) {
        for (int e = p0 + t; e < p1; e += 256) {
            uint2 pw = epackA[e];
            int dl = (pw.x >> 23) & 255;
            if ((dl >> 7) == half) {
                int r = atomicAdd(&lcur[dl & 127], 1);
                stag[r] = pw;
            }
        }
        __syncthreads();
        for (int s2 = t; s2 < ne; s2 += 256)
            epack[s0 + s2] = stag[s2];
    } else {
        // adversarial-degree fallback: per-thread per-node sequential copy
        if (t < 128) {
            int my = (half << 7) | t;
            int wpos = p0 + hist[my];
            for (int e = p0; e < p1; ++e) {
                uint2 pw = epackA[e];
                if ((int)((pw.x >> 23) & 255) == my) epack[wpos++] = pw;
            }
        }
    }
}

// ---------------------------------------------------------------------------
// Fallback CSR build (non-multisplit shapes): histogram -> scan -> scatter
// ---------------------------------------------------------------------------
__global__ __launch_bounds__(256) void hist_dst(
    const int* __restrict__ dst, int* __restrict__ counts, int nE)
{
    int e = blockIdx.x * 256 + threadIdx.x;
    if (e < nE) atomicAdd(&counts[dst[e]], 1);
}

__global__ __launch_bounds__(256) void scan_partial(
    const int* __restrict__ counts, int* __restrict__ bsum, int nN)
{
    __shared__ int s[256];
    int t = threadIdx.x;
    int i = blockIdx.x * 256 + t;
    int v = (i < nN) ? counts[i] : 0;
    s[t] = v; __syncthreads();
    for (int o = 1; o < 256; o <<= 1) {
        int u = (t >= o) ? s[t - o] : 0;
        __syncthreads(); s[t] += u; __syncthreads();
    }
    if (t == 255) bsum[blockIdx.x] = s[255];
}

__global__ __launch_bounds__(512) void scan_base(
    const int* __restrict__ bsum, int* __restrict__ bbase, int nb,
    int* __restrict__ row_off, int nN)
{
    __shared__ int s[512];
    int t = threadIdx.x;
    int v = (t < nb) ? bsum[t] : 0;
    s[t] = v; __syncthreads();
    for (int o = 1; o < 512; o <<= 1) {
        int u = (t >= o) ? s[t - o] : 0;
        __syncthreads(); s[t] += u; __syncthreads();
    }
    if (t < nb) bbase[t] = s[t] - v;
    if (t == nb - 1) row_off[nN] = s[t];
}

__global__ __launch_bounds__(256) void scan_final(
    const int* __restrict__ counts, const int* __restrict__ bbase,
    int* __restrict__ row_off, int* __restrict__ cursor, int nN)
{
    __shared__ int s[256];
    int t = threadIdx.x;
    int i = blockIdx.x * 256 + t;
    int v = (i < nN) ? counts[i] : 0;
    s[t] = v; __syncthreads();
    for (int o = 1; o < 256; o <<= 1) {
        int u = (t >= o) ? s[t - o] : 0;
        __syncthreads(); s[t] += u; __syncthreads();
    }
    if (i < nN) {
        int off = bbase[blockIdx.x] + s[t] - v;
        row_off[i] = off;
        cursor[i]  = off;
    }
}

__global__ __launch_bounds__(256) void fill_csr(
    const int* __restrict__ src, const int* __restrict__ dst,
    const float* __restrict__ ew, const int* __restrict__ ec,
    int* __restrict__ cursor, uint2* __restrict__ epack, int nE)
{
    int e = blockIdx.x * 256 + threadIdx.x;
    if (e >= nE) return;
    int p = atomicAdd(&cursor[dst[e]], 1);
    epack[p] = make_uint2((unsigned int)src[e] | ((unsigned int)ec[e] << 20),
                          __float_as_uint(ew[e]));
}

// ---------------------------------------------------------------------------
// Gather aggregation, DIMS=64: one wave per dst node, lane = dim.
// 8-wide software pipeline: 8 independent loads in flight per wave.
// ---------------------------------------------------------------------------
__global__ __launch_bounds__(256) void gather_d64(
    const ushort* __restrict__ h, const int* __restrict__ row_off,
    const uint2* __restrict__ epack, float* __restrict__ agg, int nN)
{
    int w    = (blockIdx.x * 256 + threadIdx.x) >> 6;
    int lane = threadIdx.x & 63;
    if (w >= nN) return;
    int s0 = row_off[w], s1 = row_off[w + 1];
    float acc = agg[(size_t)w * 64 + lane];
    const unsigned int un = (unsigned int)nN;
    for (int base = s0; base < s1; base += 64) {
        int m = min(64, s1 - base);
        unsigned int pk = 0; float wv = 0.f;
        if (lane < m) {
            uint2 pw = epack[base + lane];
            pk = pw.x; wv = __uint_as_float(pw.y);
        }
        int j = 0;
        for (; j + 8 <= m; j += 8) {
            unsigned int p0 = __shfl(pk, j + 0, 64), p1 = __shfl(pk, j + 1, 64);
            unsigned int p2 = __shfl(pk, j + 2, 64), p3 = __shfl(pk, j + 3, 64);
            unsigned int p4 = __shfl(pk, j + 4, 64), p5 = __shfl(pk, j + 5, 64);
            unsigned int p6 = __shfl(pk, j + 6, 64), p7 = __shfl(pk, j + 7, 64);
            float q0 = __shfl(wv, j + 0, 64), q1 = __shfl(wv, j + 1, 64);
            float q2 = __shfl(wv, j + 2, 64), q3 = __shfl(wv, j + 3, 64);
            float q4 = __shfl(wv, j + 4, 64), q5 = __shfl(wv, j + 5, 64);
            float q6 = __shfl(wv, j + 6, 64), q7 = __shfl(wv, j + 7, 64);
            ushort v0 = h[(((p0 >> 20) & 7) * un + (p0 & 0xFFFFFu)) * 64u + lane];
            ushort v1 = h[(((p1 >> 20) & 7) * un + (p1 & 0xFFFFFu)) * 64u + lane];
            ushort v2 = h[(((p2 >> 20) & 7) * un + (p2 & 0xFFFFFu)) * 64u + lane];
            ushort v3 = h[(((p3 >> 20) & 7) * un + (p3 & 0xFFFFFu)) * 64u + lane];
            ushort v4 = h[(((p4 >> 20) & 7) * un + (p4 & 0xFFFFFu)) * 64u + lane];
            ushort v5 = h[(((p5 >> 20) & 7) * un + (p5 & 0xFFFFFu)) * 64u + lane];
            ushort v6 = h[(((p6 >> 20) & 7) * un + (p6 & 0xFFFFFu)) * 64u + lane];
            ushort v7 = h[(((p7 >> 20) & 7) * un + (p7 & 0xFFFFFu)) * 64u + lane];
            acc = fmaf(q0, bf2f(v0), acc); acc = fmaf(q1, bf2f(v1), acc);
            acc = fmaf(q2, bf2f(v2), acc); acc = fmaf(q3, bf2f(v3), acc);
            acc = fmaf(q4, bf2f(v4), acc); acc = fmaf(q5, bf2f(v5), acc);
            acc = fmaf(q6, bf2f(v6), acc); acc = fmaf(q7, bf2f(v7), acc);
        }
        for (; j < m; ++j) {
            unsigned int pj = __shfl(pk, j, 64);
            float        wj = __shfl(wv, j, 64);
            ushort v = h[(((pj >> 20) & 7) * un + (pj & 0xFFFFFu)) * 64u + lane];
            acc = fmaf(wj, bf2f(v), acc);
        }
    }
    agg[(size_t)w * 64 + lane] = acc;
}

// ---------------------------------------------------------------------------
// Gather aggregation, C=40: lanes 0..39 accumulate; same 8-wide pipeline.
// ---------------------------------------------------------------------------
__global__ __launch_bounds__(256) void gather_d40(
    const ushort* __restrict__ h, const int* __restrict__ row_off,
    const uint2* __restrict__ epack, float* __restrict__ agg, int nN)
{
    int w    = (blockIdx.x * 256 + threadIdx.x) >> 6;
    int lane = threadIdx.x & 63;
    if (w >= nN) return;
    int s0 = row_off[w], s1 = row_off[w + 1];
    float acc = 0.f;
    if (lane < 40) acc = agg[(size_t)w * 40 + lane];
    const unsigned int un = (unsigned int)nN;
    for (int base = s0; base < s1; base += 64) {
        int m = min(64, s1 - base);
        unsigned int pk = 0; float wv = 0.f;
        if (lane < m) {
            uint2 pw = epack[base + lane];
            pk = pw.x; wv = __uint_as_float(pw.y);
        }
        int j = 0;
        for (; j + 8 <= m; j += 8) {
            unsigned int p0 = __shfl(pk, j + 0, 64), p1 = __shfl(pk, j + 1, 64);
            unsigned int p2 = __shfl(pk, j + 2, 64), p3 = __shfl(pk, j + 3, 64);
            unsigned int p4 = __shfl(pk, j + 4, 64), p5 = __shfl(pk, j + 5, 64);
            unsigned int p6 = __shfl(pk, j + 6, 64), p7 = __shfl(pk, j + 7, 64);
            float q0 = __shfl(wv, j + 0, 64), q1 = __shfl(wv, j + 1, 64);
            float q2 = __shfl(wv, j + 2, 64), q3 = __shfl(wv, j + 3, 64);
            float q4 = __shfl(wv, j + 4, 64), q5 = __shfl(wv, j + 5, 64);
            float q6 = __shfl(wv, j + 6, 64), q7 = __shfl(wv, j + 7, 64);
            if (lane < 40) {
                ushort v0 = h[(((p0 >> 20) & 7) * un + (p0 & 0xFFFFFu)) * 40u + lane];
                ushort v1 = h[(((p1 >> 20) & 7) * un + (p1 & 0xFFFFFu)) * 40u + lane];
                ushort v2 = h[(((p2 >> 20) & 7) * un + (p2 & 0xFFFFFu)) * 40u + lane];
                ushort v3 = h[(((p3 >> 20) & 7) * un + (p3 & 0xFFFFFu)) * 40u + lane];
                ushort v4 = h[(((p4 >> 20) & 7) * un + (p4 & 0xFFFFFu)) * 40u + lane];
                ushort v5 = h[(((p5 >> 20) & 7) * un + (p5 & 0xFFFFFu)) * 40u + lane];
                ushort v6 = h[(((p6 >> 20) & 7) * un + (p6 & 0xFFFFFu)) * 40u + lane];
                ushort v7 = h[(((p7 >> 20) & 7) * un + (p7 & 0xFFFFFu)) * 40u + lane];
                acc = fmaf(q0, bf2f(v0), acc); acc = fmaf(q1, bf2f(v1), acc);
                acc = fmaf(q2, bf2f(v2), acc); acc = fmaf(q3, bf2f(v3), acc);
                acc = fmaf(q4, bf2f(v4), acc); acc = fmaf(q5, bf2f(v5), acc);
                acc = fmaf(q6, bf2f(v6), acc); acc = fmaf(q7, bf2f(v7), acc);
            }
        }
        for (; j < m; ++j) {
            unsigned int pj = __shfl(pk, j, 64);
            float        wj = __shfl(wv, j, 64);
            if (lane < 40) {
                ushort v = h[(((pj >> 20) & 7) * un + (pj & 0xFFFFFu)) * 40u + lane];
                acc = fmaf(wj, bf2f(v), acc);
            }
        }
    }
    if (lane < 40) agg[(size_t)w * 40 + lane] = acc;
}

// ---------------------------------------------------------------------------
// Epilogue: (log_softmax(out), out)
// ---------------------------------------------------------------------------
__global__ __launch_bounds__(256) void logsoftmax_out(
    const float* __restrict__ agg2, float* __restrict__ out, int nN)
{
    int w    = (blockIdx.x * 256 + threadIdx.x) >> 6;
    int lane = threadIdx.x & 63;
    if (w >= nN) return;
    float v = -INFINITY;
    if (lane < 40) v = agg2[(size_t)w * 40 + lane];
    float m = v;
    #pragma unroll
    for (int o = 32; o > 0; o >>= 1) m = fmaxf(m, __shfl_xor(m, o, 64));
    float ex = (lane < 40) ? expf(v - m) : 0.f;
    float s = ex;
    #pragma unroll
    for (int o = 32; o > 0; o >>= 1) s += __shfl_xor(s, o, 64);
    float lse = logf(s) + m;
    if (lane < 40) {
        out[(size_t)w * 40 + lane] = v - lse;
        out[(size_t)nN * 40 + (size_t)w * 40 + lane] = v;
    }
}

// ---------------------------------------------------------------------------
extern "C" void kernel_launch(void* const* d_in, const int* in_sizes, int n_in,
                              void* d_out, int out_size, void* d_ws, size_t ws_size,
                              hipStream_t stream)
{
    const float* x       = (const float*)d_in[0];
    const int*   eidx    = (const int*)  d_in[1];
    const float* ew      = (const float*)d_in[2];
    const int*   ec      = (const int*)  d_in[3];
    const float* W1_rel  = (const float*)d_in[4];
    const float* W1_root = (const float*)d_in[5];
    const float* b1      = (const float*)d_in[6];
    const float* W2_rel  = (const float*)d_in[7];
    const float* W2_root = (const float*)d_in[8];
    const float* b2      = (const float*)d_in[9];

    const int nN = in_sizes[0] / 128;   // 100000
    const int nE = in_sizes[2];         // 3200000
    const int* src = eidx;
    const int* dst = eidx + nE;

    const int nBkt = (nN + 255) >> 8;          // 391 stage-1 buckets
    const int nBlk = (nE + CH - 1) / CH;       // 782 multisplit chunks

    char* w8 = (char*)d_ws;
    size_t off = 0;
    auto alloc = [&](size_t bytes) {
        void* p = w8 + off;
        off += (bytes + 255) & ~(size_t)255;
        return p;
    };
    ushort* h      = (ushort*)alloc((size_t)RELS * nN * 64 * 2);
    ushort* xb     = (ushort*)alloc((size_t)nN * 128 * 2);
    float*  agg1   = (float*) alloc((size_t)nN * 64 * 4);
    float*  agg2   = (float*) alloc((size_t)nN * 40 * 4);
    int*    counts = (int*)   alloc((size_t)nN * 4);
    int*    row_off= (int*)   alloc(((size_t)nN + 1) * 4);
    int*    cursor = (int*)   alloc((size_t)nN * 4);
    int*    tsum   = (int*)   alloc(4096);   // also bsum in fallback
    int*    bktbase= (int*)   alloc(4096);   // also bbase in fallback
    uint2*  epack  = (uint2*) alloc((size_t)nE * 8);
    ushort* w1t    = (ushort*)alloc((size_t)9 * 64 * 128 * 2);
    ushort* w2t    = (ushort*)alloc((size_t)9 * 48 * 64 * 2);
    int*    cnt    = (int*)   alloc((size_t)nBlk * nBkt * 4);
    int*    offm   = (int*)   alloc((size_t)nBkt * nBlk * 4);
    uint2*  epackA = (uint2*) alloc((size_t)nE * 8);
    const bool multisplit = (off <= ws_size) && (nBlk <= 1024) && (nBkt <= 512)
                            && (nN < (1 << 20));
    ushort* y1b = xb;   // x bf16 dead after layer-1 GEMMs

    const dim3 blk(256);
    const int NB_scan     = (nN + 255) / 256;
    const int gemm_blocks = (nN + 63) / 64;
    const int edge_blocks = (nE + 255) / 256;
    const int wave_blocks = (int)(((size_t)nN * 64 + 255) / 256);
    const int ls_blocks   = (nN + 3) / 4;

    if (multisplit) {
        // ---- CSR build: zero global atomics; row_off derived in reorder2
        mcount<<<nBlk, blk, 0, stream>>>(dst, cnt, nE, nBkt);
        scanB<<<nBkt, dim3(1024), 0, stream>>>(cnt, offm, tsum, nBlk, nBkt);
        scanT<<<1, dim3(512), 0, stream>>>(tsum, bktbase, row_off, nBkt, nN);
        mscatter<<<nBlk, dim3(512), 0, stream>>>(src, dst, ew, ec, cnt, offm,
                                                 bktbase, epackA, nE, nBlk, nBkt);
        reorder2<<<(nN + 127) / 128, blk, 0, stream>>>(epackA, bktbase,
                                                       row_off, epack, nN);
    } else {
        // ---- fallback: histogram + scan + scatter fill
        hipMemsetAsync(counts, 0, (size_t)nN * 4, stream);
        hist_dst<<<edge_blocks, blk, 0, stream>>>(dst, counts, nE);
        scan_partial<<<NB_scan, blk, 0, stream>>>(counts, tsum, nN);
        scan_base<<<1, dim3(512), 0, stream>>>(tsum, bktbase, NB_scan, row_off, nN);
        scan_final<<<NB_scan, blk, 0, stream>>>(counts, bktbase, row_off, cursor, nN);
        fill_csr<<<edge_blocks, blk, 0, stream>>>(src, dst, ew, ec, cursor, epack, nE);
    }

    // ---- weight/input prep (bf16)
    cast_f32_bf16x4<<<(nN * 128 / 4 + 255) / 256, blk, 0, stream>>>(x, xb, nN * 128 / 4);
    conv_w1<<<(9 * 64 * 128 + 255) / 256, blk, 0, stream>>>(W1_rel, W1_root, w1t);
    conv_w2<<<(9 * 48 * 64 + 255) / 256, blk, 0, stream>>>(W2_rel, W2_root, w2t);

    // ---- Layer 1
    gemm1_mfma<<<dim3(gemm_blocks, 9), blk, 0, stream>>>(xb, w1t, h, agg1, b1, nN);
    gather_d64<<<wave_blocks, blk, 0, stream>>>(h, row_off, epack, agg1, nN);

    // ---- Layer 2
    cast_relu_bf16x4<<<(nN * 64 / 4 + 255) / 256, blk, 0, stream>>>(agg1, y1b, nN * 64 / 4);
    gemm2_mfma<<<dim3(gemm_blocks, 9), blk, 0, stream>>>(y1b, w2t, h, agg2, b2, nN);
    gather_d40<<<wave_blocks, blk, 0, stream>>>(h, row_off, epack, agg2, nN);

    // ---- Epilogue
    logsoftmax_out<<<ls_blocks, blk, 0, stream>>>(agg2, (float*)d_out, nN);
}

// Round 8
// 386.792 us; speedup vs baseline: 3.2094x; 1.0851x over previous
//
#include <hip/hip_runtime.h>
#include <hip/hip_bf16.h>
#include <cmath>

// WRGCN: 2-layer weighted relational GCN.
// N=100000, E=3200000, R=8, F_IN=128, DIMS=64, C=40.
// Lessons encoded:
//  - scattered partial-line stores/atomics cost a full 64B line each
//    (r4/r5/r6) -> all edge-rate memory ops LDS-staged, flushed linearly.
//  - never funnel E atomics into few cursors (r4: 782 cursors -> 749us).
//  - CSR build has zero global atomics (r7): multisplit counts + scans.
//  - gathers (r7: 53% VALUBusy): paired-edge dword loads halve instr/edge;
//    relu-cast and log_softmax fused into gather epilogues.

#define RELS 8
#define CH 4096       // edges per multisplit chunk
#define ST2CAP 6144   // stage-2 LDS staging capacity (mean 4096)

typedef __attribute__((ext_vector_type(8))) short bf16x8;
typedef __attribute__((ext_vector_type(4))) float f32x4;

static __device__ __forceinline__ ushort f2bf(float f) {
    __hip_bfloat16 b = __float2bfloat16(f);
    return *reinterpret_cast<ushort*>(&b);
}

// ---------------------------------------------------------------------------
// Casts / weight prep
// ---------------------------------------------------------------------------
__global__ __launch_bounds__(256) void cast_f32_bf16x4(
    const float* __restrict__ in, ushort* __restrict__ out, int n4)
{
    int i = blockIdx.x * 256 + threadIdx.x;
    if (i >= n4) return;
    float4 v = ((const float4*)in)[i];
    ushort4 o;
    o.x = f2bf(v.x); o.y = f2bf(v.y); o.z = f2bf(v.z); o.w = f2bf(v.w);
    ((ushort4*)out)[i] = o;
}

// w1t[r][c][k]: r in [0,9): r<8 from W1_rel [R][128][64]; r==8 from W1_root.
__global__ __launch_bounds__(256) void conv_w1(
    const float* __restrict__ Wrel, const float* __restrict__ Wroot,
    ushort* __restrict__ wt)
{
    int i = blockIdx.x * 256 + threadIdx.x;
    if (i >= 9 * 64 * 128) return;
    int r = i >> 13, c = (i >> 7) & 63, k = i & 127;
    float v = (r < 8) ? Wrel[((size_t)r * 128 + k) * 64 + c]
                      : Wroot[(size_t)k * 64 + c];
    wt[i] = f2bf(v);
}

// w2t[r][c][k]: r in [0,9), c in [0,48) (pad 40..47 = 0), k in [0,64).
__global__ __launch_bounds__(256) void conv_w2(
    const float* __restrict__ Wrel, const float* __restrict__ Wroot,
    ushort* __restrict__ wt)
{
    int i = blockIdx.x * 256 + threadIdx.x;
    if (i >= 9 * 48 * 64) return;
    int r = i / (48 * 64), rem = i - r * (48 * 64);
    int c = rem >> 6, k = rem & 63;
    float v = 0.f;
    if (c < 40)
        v = (r < 8) ? Wrel[((size_t)r * 64 + k) * 40 + c]
                    : Wroot[(size_t)k * 40 + c];
    wt[i] = f2bf(v);
}

// ---------------------------------------------------------------------------
// Layer-1 GEMMs (MFMA bf16), blockIdx.y in [0,9):
//   y<8 : h[y][n][0:64] = xb[n][0:128] @ W1_rel[y]      (bf16 out)
//   y==8: agg1[n][0:64] = xb[n][0:128] @ W1_root + b1   (f32 out)
// ---------------------------------------------------------------------------
__global__ __launch_bounds__(256) void gemm1_mfma(
    const ushort* __restrict__ xb, const ushort* __restrict__ w1t,
    ushort* __restrict__ hout, float* __restrict__ agg1,
    const float* __restrict__ b1, int nN)
{
    __shared__ ushort xs[64 * 128];
    __shared__ ushort wt[64 * 128];
    const int y    = blockIdx.y;
    const int tid  = threadIdx.x;
    const int n0   = blockIdx.x * 64;
    const int nmax = nN - n0;
    const bool isroot = (y == 8);
    ushort* out = hout + (size_t)y * nN * 64;
    const ushort* wsrc = w1t + (size_t)y * 64 * 128;

    for (int i = tid; i < 1024; i += 256) {
        int row = i >> 4, ch = i & 15;
        uint4 v = make_uint4(0u, 0u, 0u, 0u);
        if (row < nmax)
            v = *(const uint4*)(xb + (size_t)(n0 + row) * 128 + ch * 8);
        int off = (row * 256 + ch * 16) ^ ((row & 7) << 4);
        *(uint4*)((char*)xs + off) = v;
    }
    for (int i = tid; i < 1024; i += 256) {
        int row = i >> 4, ch = i & 15;
        uint4 v = *(const uint4*)(wsrc + (size_t)row * 128 + ch * 8);
        int off = (row * 256 + ch * 16) ^ ((row & 7) << 4);
        *(uint4*)((char*)wt + off) = v;
    }
    __syncthreads();

    const int wv   = tid >> 6;
    const int lane = tid & 63;
    const int lr   = wv * 16 + (lane & 15);
    const int kgb  = (lane >> 4) * 8;

    f32x4 acc[4] = {{0.f,0.f,0.f,0.f},{0.f,0.f,0.f,0.f},
                    {0.f,0.f,0.f,0.f},{0.f,0.f,0.f,0.f}};

    #pragma unroll
    for (int ks = 0; ks < 4; ++ks) {
        int kb = (ks * 32 + kgb) * 2;
        int aoff = (lr * 256 + kb) ^ ((lr & 7) << 4);
        bf16x8 a = *(const bf16x8*)((const char*)xs + aoff);
        #pragma unroll
        for (int ct = 0; ct < 4; ++ct) {
            int col = ct * 16 + (lane & 15);
            int boff = (col * 256 + kb) ^ ((col & 7) << 4);
            bf16x8 b = *(const bf16x8*)((const char*)wt + boff);
            acc[ct] = __builtin_amdgcn_mfma_f32_16x16x32_bf16(a, b, acc[ct], 0, 0, 0);
        }
    }

    #pragma unroll
    for (int ct = 0; ct < 4; ++ct) {
        int col = ct * 16 + (lane & 15);
        #pragma unroll
        for (int reg = 0; reg < 4; ++reg) {
            int row = wv * 16 + (lane >> 4) * 4 + reg;
            if (row < nmax) {
                if (isroot)
                    agg1[(size_t)(n0 + row) * 64 + col] = acc[ct][reg] + b1[col];
                else
                    out[(size_t)(n0 + row) * 64 + col] = f2bf(acc[ct][reg]);
            }
        }
    }
}

// ---------------------------------------------------------------------------
// Layer-2 GEMMs (MFMA bf16), blockIdx.y in [0,9):
//   y<8 : h2[y][n][0:40] = y1b[n][0:64] @ W2_rel[y]     (bf16 out)
//   y==8: agg2[n][0:40] = y1b[n][0:64] @ W2_root + b2   (f32 out)
// ---------------------------------------------------------------------------
__global__ __launch_bounds__(256) void gemm2_mfma(
    const ushort* __restrict__ y1b, const ushort* __restrict__ w2t,
    ushort* __restrict__ hout, float* __restrict__ agg2,
    const float* __restrict__ b2, int nN)
{
    __shared__ ushort ys[64 * 64];
    __shared__ ushort wt[48 * 64];
    const int y    = blockIdx.y;
    const int tid  = threadIdx.x;
    const int n0   = blockIdx.x * 64;
    const int nmax = nN - n0;
    const bool isroot = (y == 8);
    ushort* out = hout + (size_t)y * nN * 40;
    const ushort* wsrc = w2t + (size_t)y * 48 * 64;

    for (int i = tid; i < 512; i += 256) {
        int row = i >> 3, ch = i & 7;
        uint4 v = make_uint4(0u, 0u, 0u, 0u);
        if (row < nmax)
            v = *(const uint4*)(y1b + (size_t)(n0 + row) * 64 + ch * 8);
        int off = (row * 128 + ch * 16) ^ ((row & 7) << 4);
        *(uint4*)((char*)ys + off) = v;
    }
    for (int i = tid; i < 384; i += 256) {
        int row = i >> 3, ch = i & 7;
        uint4 v = *(const uint4*)(wsrc + (size_t)row * 64 + ch * 8);
        int off = (row * 128 + ch * 16) ^ ((row & 7) << 4);
        *(uint4*)((char*)wt + off) = v;
    }
    __syncthreads();

    const int wv   = tid >> 6;
    const int lane = tid & 63;
    const int lr   = wv * 16 + (lane & 15);
    const int kgb  = (lane >> 4) * 8;

    f32x4 acc[3] = {{0.f,0.f,0.f,0.f},{0.f,0.f,0.f,0.f},{0.f,0.f,0.f,0.f}};

    #pragma unroll
    for (int ks = 0; ks < 2; ++ks) {
        int kb = (ks * 32 + kgb) * 2;
        int aoff = (lr * 128 + kb) ^ ((lr & 7) << 4);
        bf16x8 a = *(const bf16x8*)((const char*)ys + aoff);
        #pragma unroll
        for (int ct = 0; ct < 3; ++ct) {
            int col = ct * 16 + (lane & 15);
            int boff = (col * 128 + kb) ^ ((col & 7) << 4);
            bf16x8 b = *(const bf16x8*)((const char*)wt + boff);
            acc[ct] = __builtin_amdgcn_mfma_f32_16x16x32_bf16(a, b, acc[ct], 0, 0, 0);
        }
    }

    #pragma unroll
    for (int ct = 0; ct < 3; ++ct) {
        int col = ct * 16 + (lane & 15);
        if (col < 40) {
            #pragma unroll
            for (int reg = 0; reg < 4; ++reg) {
                int row = wv * 16 + (lane >> 4) * 4 + reg;
                if (row < nmax) {
                    if (isroot)
                        agg2[(size_t)(n0 + row) * 40 + col] = acc[ct][reg] + b2[col];
                    else
                        out[(size_t)(n0 + row) * 40 + col] = f2bf(acc[ct][reg]);
                }
            }
        }
    }
}

// ---------------------------------------------------------------------------
// CSR build: two-stage multisplit, zero global atomics.
// payload pk: bits 0..19 src, 20..22 color, 23..30 dst&255
// ---------------------------------------------------------------------------
__global__ __launch_bounds__(256) void mcount(
    const int* __restrict__ dst, int* __restrict__ cnt, int nE, int nBkt)
{
    __shared__ int hist[512];
    const int blk = blockIdx.x;
    const int t = threadIdx.x;
    for (int i = t; i < nBkt; i += 256) hist[i] = 0;
    __syncthreads();
    const int e0 = blk * CH;
    const int eend = min(e0 + CH, nE);
    for (int e = e0 + t; e < eend; e += 256)
        atomicAdd(&hist[dst[e] >> 8], 1);
    __syncthreads();
    for (int i = t; i < nBkt; i += 256)
        cnt[(size_t)blk * nBkt + i] = hist[i];
}

__global__ __launch_bounds__(1024) void scanB(
    const int* __restrict__ cnt, int* __restrict__ offm_rel,
    int* __restrict__ tsum, int nBlk, int nBkt)
{
    __shared__ int s[1024];
    const int bkt = blockIdx.x;
    const int t = threadIdx.x;
    int v = (t < nBlk) ? cnt[(size_t)t * nBkt + bkt] : 0;
    s[t] = v; __syncthreads();
    for (int o = 1; o < 1024; o <<= 1) {
        int u = (t >= o) ? s[t - o] : 0;
        __syncthreads(); s[t] += u; __syncthreads();
    }
    if (t < nBlk) offm_rel[(size_t)bkt * nBlk + t] = s[t] - v;
    if (t == nBlk - 1) tsum[bkt] = s[t];
}

__global__ __launch_bounds__(512) void scanT(
    const int* __restrict__ tsum, int* __restrict__ bktbase,
    int* __restrict__ row_off, int nBkt, int nN)
{
    __shared__ int s[512];
    const int t = threadIdx.x;
    int v = (t < nBkt) ? tsum[t] : 0;
    s[t] = v; __syncthreads();
    for (int o = 1; o < 512; o <<= 1) {
        int u = (t >= o) ? s[t - o] : 0;
        __syncthreads(); s[t] += u; __syncthreads();
    }
    if (t < nBkt) bktbase[t] = s[t] - v;
    if (t == nBkt - 1) { bktbase[nBkt] = s[t]; row_off[nN] = s[t]; }
}

__global__ __launch_bounds__(512) void mscatter(
    const int* __restrict__ src, const int* __restrict__ dst,
    const float* __restrict__ ew, const int* __restrict__ ec,
    const int* __restrict__ cnt, const int* __restrict__ offm_rel,
    const int* __restrict__ bktbase,
    uint2* __restrict__ epackA, int nE, int nBlk, int nBkt)
{
    __shared__ uint2 stag[CH];
    __shared__ int lbase[512];
    __shared__ int lcur[512];
    __shared__ int goff[512];
    const int blk = blockIdx.x;
    const int t = threadIdx.x;

    int v = (t < nBkt) ? cnt[(size_t)blk * nBkt + t] : 0;
    lbase[t] = v; __syncthreads();
    for (int o = 1; o < 512; o <<= 1) {
        int u = (t >= o) ? lbase[t - o] : 0;
        __syncthreads(); lbase[t] += u; __syncthreads();
    }
    int excl = lbase[t] - v;
    __syncthreads();
    lbase[t] = excl;
    lcur[t] = excl;
    goff[t] = (t < nBkt) ? bktbase[t] + offm_rel[(size_t)t * nBlk + blk] : 0;
    __syncthreads();

    const int e0 = blk * CH;
    const int eend = min(e0 + CH, nE);
    const int ntot = eend - e0;
    for (int e = e0 + t; e < eend; e += 512) {
        int d = dst[e];
        int bkt = d >> 8;
        unsigned int pk = (unsigned int)src[e] | ((unsigned int)ec[e] << 20)
                        | ((unsigned int)(d & 255) << 23);
        int r = atomicAdd(&lcur[bkt], 1);
        stag[r] = make_uint2(pk, __float_as_uint(ew[e]));
    }
    __syncthreads();
    for (int s2 = t; s2 < ntot; s2 += 512) {
        int lo = 0, hi = nBkt - 1;
        while (lo < hi) {
            int mid = (lo + hi + 1) >> 1;
            if (lbase[mid] <= s2) lo = mid; else hi = mid - 1;
        }
        epackA[goff[lo] + (s2 - lbase[lo])] = stag[s2];
    }
}

// stage 2: one block per 128-node half of a 256-node bucket.
__global__ __launch_bounds__(256) void reorder2(
    const uint2* __restrict__ epackA, const int* __restrict__ bktbase,
    int* __restrict__ row_off, uint2* __restrict__ epack, int nN)
{
    __shared__ uint2 stag[ST2CAP];
    __shared__ int hist[256];
    __shared__ int s[256];
    __shared__ int lcur[128];
    const int b    = blockIdx.x;
    const int n0   = b << 7;
    const int pb   = b >> 1;
    const int half = b & 1;
    const int p0 = bktbase[pb];
    const int p1 = bktbase[pb + 1];
    const int t = threadIdx.x;

    hist[t] = 0;
    __syncthreads();
    const unsigned int* ax = (const unsigned int*)epackA;
    for (int e = p0 + t; e < p1; e += 256)
        atomicAdd(&hist[(ax[2 * (size_t)e] >> 23) & 255], 1);
    __syncthreads();
    int v = hist[t];
    s[t] = v; __syncthreads();
    for (int o = 1; o < 256; o <<= 1) {
        int u = (t >= o) ? s[t - o] : 0;
        __syncthreads(); s[t] += u; __syncthreads();
    }
    hist[t] = s[t] - v;
    __syncthreads();

    const int hb0 = hist[half << 7];
    const int hb1 = (half == 0) ? hist[128] : (p1 - p0);
    const int ne  = hb1 - hb0;
    const int s0  = p0 + hb0;

    if (t < 128) {
        int idx = n0 + t;
        if (idx < nN) row_off[idx] = p0 + hist[(half << 7) + t];
        lcur[t] = hist[(half << 7) + t] - hb0;
    }
    __syncthreads();

    if (ne <= ST2CAP) {
        for (int e = p0 + t; e < p1; e += 256) {
            uint2 pw = epackA[e];
            int dl = (pw.x >> 23) & 255;
            if ((dl >> 7) == half) {
                int r = atomicAdd(&lcur[dl & 127], 1);
                stag[r] = pw;
            }
        }
        __syncthreads();
        for (int s2 = t; s2 < ne; s2 += 256)
            epack[s0 + s2] = stag[s2];
    } else {
        if (t < 128) {
            int my = (half << 7) | t;
            int wpos = p0 + hist[my];
            for (int e = p0; e < p1; ++e) {
                uint2 pw = epackA[e];
                if ((int)((pw.x >> 23) & 255) == my) epack[wpos++] = pw;
            }
        }
    }
}

// ---------------------------------------------------------------------------
// Fallback CSR build (non-multisplit shapes)
// ---------------------------------------------------------------------------
__global__ __launch_bounds__(256) void hist_dst(
    const int* __restrict__ dst, int* __restrict__ counts, int nE)
{
    int e = blockIdx.x * 256 + threadIdx.x;
    if (e < nE) atomicAdd(&counts[dst[e]], 1);
}

__global__ __launch_bounds__(256) void scan_partial(
    const int* __restrict__ counts, int* __restrict__ bsum, int nN)
{
    __shared__ int s[256];
    int t = threadIdx.x;
    int i = blockIdx.x * 256 + t;
    int v = (i < nN) ? counts[i] : 0;
    s[t] = v; __syncthreads();
    for (int o = 1; o < 256; o <<= 1) {
        int u = (t >= o) ? s[t - o] : 0;
        __syncthreads(); s[t] += u; __syncthreads();
    }
    if (t == 255) bsum[blockIdx.x] = s[255];
}

__global__ __launch_bounds__(512) void scan_base(
    const int* __restrict__ bsum, int* __restrict__ bbase, int nb,
    int* __restrict__ row_off, int nN)
{
    __shared__ int s[512];
    int t = threadIdx.x;
    int v = (t < nb) ? bsum[t] : 0;
    s[t] = v; __syncthreads();
    for (int o = 1; o < 512; o <<= 1) {
        int u = (t >= o) ? s[t - o] : 0;
        __syncthreads(); s[t] += u; __syncthreads();
    }
    if (t < nb) bbase[t] = s[t] - v;
    if (t == nb - 1) row_off[nN] = s[t];
}

__global__ __launch_bounds__(256) void scan_final(
    const int* __restrict__ counts, const int* __restrict__ bbase,
    int* __restrict__ row_off, int* __restrict__ cursor, int nN)
{
    __shared__ int s[256];
    int t = threadIdx.x;
    int i = blockIdx.x * 256 + t;
    int v = (i < nN) ? counts[i] : 0;
    s[t] = v; __syncthreads();
    for (int o = 1; o < 256; o <<= 1) {
        int u = (t >= o) ? s[t - o] : 0;
        __syncthreads(); s[t] += u; __syncthreads();
    }
    if (i < nN) {
        int off = bbase[blockIdx.x] + s[t] - v;
        row_off[i] = off;
        cursor[i]  = off;
    }
}

__global__ __launch_bounds__(256) void fill_csr(
    const int* __restrict__ src, const int* __restrict__ dst,
    const float* __restrict__ ew, const int* __restrict__ ec,
    int* __restrict__ cursor, uint2* __restrict__ epack, int nE)
{
    int e = blockIdx.x * 256 + threadIdx.x;
    if (e >= nE) return;
    int p = atomicAdd(&cursor[dst[e]], 1);
    epack[p] = make_uint2((unsigned int)src[e] | ((unsigned int)ec[e] << 20),
                          __float_as_uint(ew[e]));
}

// ---------------------------------------------------------------------------
// Gather layer 1 + fused relu/bf16 cast. One wave per dst node.
// 2 edges in flight: half=lane>>5 picks the edge, hl=lane&31 picks dim pair
// (dims 2hl,2hl+1 via one dword load). Output y1b = bf16(relu(agg)).
// ---------------------------------------------------------------------------
__global__ __launch_bounds__(256) void gather_relu_d64(
    const ushort* __restrict__ h, const int* __restrict__ row_off,
    const uint2* __restrict__ epack, const float* __restrict__ agg1,
    ushort* __restrict__ y1b, int nN)
{
    int w    = (blockIdx.x * 256 + threadIdx.x) >> 6;
    int lane = threadIdx.x & 63;
    if (w >= nN) return;
    const int half = lane >> 5;
    const int hl   = lane & 31;
    const unsigned int un = (unsigned int)nN;
    int s0 = row_off[w], s1 = row_off[w + 1];

    float a0 = 0.f, a1 = 0.f;
    if (half == 0) {
        float2 iv = *(const float2*)(agg1 + (size_t)w * 64 + 2 * hl);
        a0 = iv.x; a1 = iv.y;
    }

    for (int base = s0; base < s1; base += 64) {
        int m = min(64, s1 - base);
        unsigned int pk = 0; float wv = 0.f;
        if (lane < m) {
            uint2 pw = epack[base + lane];
            pk = pw.x; wv = __uint_as_float(pw.y);
        }
        int j = 0;
        for (; j + 8 <= m; j += 8) {
            unsigned int pA = __shfl(pk, j + 0 + half, 64);
            unsigned int pB = __shfl(pk, j + 2 + half, 64);
            unsigned int pC = __shfl(pk, j + 4 + half, 64);
            unsigned int pD = __shfl(pk, j + 6 + half, 64);
            float qA = __shfl(wv, j + 0 + half, 64);
            float qB = __shfl(wv, j + 2 + half, 64);
            float qC = __shfl(wv, j + 4 + half, 64);
            float qD = __shfl(wv, j + 6 + half, 64);
            unsigned int vA = *(const unsigned int*)(h + ((((pA >> 20) & 7) * un + (pA & 0xFFFFFu)) * 64u + 2u * hl));
            unsigned int vB = *(const unsigned int*)(h + ((((pB >> 20) & 7) * un + (pB & 0xFFFFFu)) * 64u + 2u * hl));
            unsigned int vC = *(const unsigned int*)(h + ((((pC >> 20) & 7) * un + (pC & 0xFFFFFu)) * 64u + 2u * hl));
            unsigned int vD = *(const unsigned int*)(h + ((((pD >> 20) & 7) * un + (pD & 0xFFFFFu)) * 64u + 2u * hl));
            a0 = fmaf(qA, __uint_as_float(vA << 16), a0);
            a1 = fmaf(qA, __uint_as_float(vA & 0xFFFF0000u), a1);
            a0 = fmaf(qB, __uint_as_float(vB << 16), a0);
            a1 = fmaf(qB, __uint_as_float(vB & 0xFFFF0000u), a1);
            a0 = fmaf(qC, __uint_as_float(vC << 16), a0);
            a1 = fmaf(qC, __uint_as_float(vC & 0xFFFF0000u), a1);
            a0 = fmaf(qD, __uint_as_float(vD << 16), a0);
            a1 = fmaf(qD, __uint_as_float(vD & 0xFFFF0000u), a1);
        }
        for (; j + 2 <= m; j += 2) {
            unsigned int p = __shfl(pk, j + half, 64);
            float q = __shfl(wv, j + half, 64);
            unsigned int v = *(const unsigned int*)(h + ((((p >> 20) & 7) * un + (p & 0xFFFFFu)) * 64u + 2u * hl));
            a0 = fmaf(q, __uint_as_float(v << 16), a0);
            a1 = fmaf(q, __uint_as_float(v & 0xFFFF0000u), a1);
        }
        if (j < m) {   // odd tail: half 0 only
            unsigned int p = __shfl(pk, j, 64);
            float q = __shfl(wv, j, 64);
            if (half == 0) {
                unsigned int v = *(const unsigned int*)(h + ((((p >> 20) & 7) * un + (p & 0xFFFFFu)) * 64u + 2u * hl));
                a0 = fmaf(q, __uint_as_float(v << 16), a0);
                a1 = fmaf(q, __uint_as_float(v & 0xFFFF0000u), a1);
            }
        }
    }
    a0 += __shfl_xor(a0, 32, 64);
    a1 += __shfl_xor(a1, 32, 64);
    if (half == 0) {
        unsigned int b0 = f2bf(fmaxf(a0, 0.f));
        unsigned int b1 = f2bf(fmaxf(a1, 0.f));
        *(unsigned int*)(y1b + (size_t)w * 64 + 2 * hl) = b0 | (b1 << 16);
    }
}

// ---------------------------------------------------------------------------
// Gather layer 2 + fused log_softmax epilogue. One wave per dst node.
// 3 edges in flight: g=lane/20 picks the edge, hl=lane-20g picks dim pair
// (dims 2hl,2hl+1, 40 dims = 20 pairs); lanes 60..63 idle. Writes both
// outputs (log_softmax and raw) directly to d_out.
// ---------------------------------------------------------------------------
__global__ __launch_bounds__(256) void gather_lsm_d40(
    const ushort* __restrict__ h, const int* __restrict__ row_off,
    const uint2* __restrict__ epack, const float* __restrict__ agg2,
    float* __restrict__ out, int nN)
{
    int w    = (blockIdx.x * 256 + threadIdx.x) >> 6;
    int lane = threadIdx.x & 63;
    if (w >= nN) return;
    const int g  = lane / 20;          // 0..2 active, 3 idle
    const int hl = lane - g * 20;
    const unsigned int un = (unsigned int)nN;
    int s0 = row_off[w], s1 = row_off[w + 1];

    float a0 = 0.f, a1 = 0.f;
    if (g == 0) {
        float2 iv = *(const float2*)(agg2 + (size_t)w * 40 + 2 * hl);
        a0 = iv.x; a1 = iv.y;
    }

    for (int base = s0; base < s1; base += 64) {
        int m = min(64, s1 - base);
        unsigned int pk = 0; float wv = 0.f;
        if (lane < m) {
            uint2 pw = epack[base + lane];
            pk = pw.x; wv = __uint_as_float(pw.y);
        }
        int j = 0;
        for (; j + 6 <= m; j += 6) {
            unsigned int pA = __shfl(pk, j + g, 64);
            unsigned int pB = __shfl(pk, j + 3 + g, 64);
            float qA = __shfl(wv, j + g, 64);
            float qB = __shfl(wv, j + 3 + g, 64);
            unsigned int vA = *(const unsigned int*)(h + ((((pA >> 20) & 7) * un + (pA & 0xFFFFFu)) * 40u + 2u * hl));
            unsigned int vB = *(const unsigned int*)(h + ((((pB >> 20) & 7) * un + (pB & 0xFFFFFu)) * 40u + 2u * hl));
            a0 = fmaf(qA, __uint_as_float(vA << 16), a0);
            a1 = fmaf(qA, __uint_as_float(vA & 0xFFFF0000u), a1);
            a0 = fmaf(qB, __uint_as_float(vB << 16), a0);
            a1 = fmaf(qB, __uint_as_float(vB & 0xFFFF0000u), a1);
        }
        for (; j + 3 <= m; j += 3) {
            unsigned int p = __shfl(pk, j + g, 64);
            float q = __shfl(wv, j + g, 64);
            unsigned int v = *(const unsigned int*)(h + ((((p >> 20) & 7) * un + (p & 0xFFFFFu)) * 40u + 2u * hl));
            a0 = fmaf(q, __uint_as_float(v << 16), a0);
            a1 = fmaf(q, __uint_as_float(v & 0xFFFF0000u), a1);
        }
        for (; j < m; ++j) {   // tail 1-2 edges: group 0 only
            unsigned int p = __shfl(pk, j, 64);
            float q = __shfl(wv, j, 64);
            if (g == 0) {
                unsigned int v = *(const unsigned int*)(h + ((((p >> 20) & 7) * un + (p & 0xFFFFFu)) * 40u + 2u * hl));
                a0 = fmaf(q, __uint_as_float(v << 16), a0);
                a1 = fmaf(q, __uint_as_float(v & 0xFFFF0000u), a1);
            }
        }
    }
    // combine the 3 edge-groups (values live at lanes hl, hl+20, hl+40)
    float b0 = __shfl(a0, hl + 20, 64), c0 = __shfl(a0, hl + 40, 64);
    float b1 = __shfl(a1, hl + 20, 64), c1 = __shfl(a1, hl + 40, 64);
    a0 += b0 + c0;
    a1 += b1 + c1;

    // log_softmax over the 40 dims (pairs in lanes 0..19)
    float mx = (g == 0) ? fmaxf(a0, a1) : -INFINITY;
    #pragma unroll
    for (int o = 32; o > 0; o >>= 1) mx = fmaxf(mx, __shfl_xor(mx, o, 64));
    float ex = (g == 0) ? (expf(a0 - mx) + expf(a1 - mx)) : 0.f;
    #pragma unroll
    for (int o = 32; o > 0; o >>= 1) ex += __shfl_xor(ex, o, 64);
    float lse = logf(ex) + mx;

    if (g == 0) {
        *(float2*)(out + (size_t)w * 40 + 2 * hl) = make_float2(a0 - lse, a1 - lse);
        *(float2*)(out + (size_t)nN * 40 + (size_t)w * 40 + 2 * hl) = make_float2(a0, a1);
    }
}

// ---------------------------------------------------------------------------
extern "C" void kernel_launch(void* const* d_in, const int* in_sizes, int n_in,
                              void* d_out, int out_size, void* d_ws, size_t ws_size,
                              hipStream_t stream)
{
    const float* x       = (const float*)d_in[0];
    const int*   eidx    = (const int*)  d_in[1];
    const float* ew      = (const float*)d_in[2];
    const int*   ec      = (const int*)  d_in[3];
    const float* W1_rel  = (const float*)d_in[4];
    const float* W1_root = (const float*)d_in[5];
    const float* b1      = (const float*)d_in[6];
    const float* W2_rel  = (const float*)d_in[7];
    const float* W2_root = (const float*)d_in[8];
    const float* b2      = (const float*)d_in[9];

    const int nN = in_sizes[0] / 128;   // 100000
    const int nE = in_sizes[2];         // 3200000
    const int* src = eidx;
    const int* dst = eidx + nE;

    const int nBkt = (nN + 255) >> 8;          // 391 stage-1 buckets
    const int nBlk = (nE + CH - 1) / CH;       // 782 multisplit chunks

    char* w8 = (char*)d_ws;
    size_t off = 0;
    auto alloc = [&](size_t bytes) {
        void* p = w8 + off;
        off += (bytes + 255) & ~(size_t)255;
        return p;
    };
    ushort* h      = (ushort*)alloc((size_t)RELS * nN * 64 * 2);
    ushort* xb     = (ushort*)alloc((size_t)nN * 128 * 2);
    float*  agg1   = (float*) alloc((size_t)nN * 64 * 4);
    float*  agg2   = (float*) alloc((size_t)nN * 40 * 4);
    int*    counts = (int*)   alloc((size_t)nN * 4);
    int*    row_off= (int*)   alloc(((size_t)nN + 1) * 4);
    int*    cursor = (int*)   alloc((size_t)nN * 4);
    int*    tsum   = (int*)   alloc(4096);
    int*    bktbase= (int*)   alloc(4096);
    uint2*  epack  = (uint2*) alloc((size_t)nE * 8);
    ushort* w1t    = (ushort*)alloc((size_t)9 * 64 * 128 * 2);
    ushort* w2t    = (ushort*)alloc((size_t)9 * 48 * 64 * 2);
    int*    cnt    = (int*)   alloc((size_t)nBlk * nBkt * 4);
    int*    offm   = (int*)   alloc((size_t)nBkt * nBlk * 4);
    uint2*  epackA = (uint2*) alloc((size_t)nE * 8);
    const bool multisplit = (off <= ws_size) && (nBlk <= 1024) && (nBkt <= 512)
                            && (nN < (1 << 20));
    ushort* y1b = xb;   // x bf16 dead after layer-1 GEMMs

    const dim3 blk(256);
    const int NB_scan     = (nN + 255) / 256;
    const int gemm_blocks = (nN + 63) / 64;
    const int edge_blocks = (nE + 255) / 256;
    const int wave_blocks = (int)(((size_t)nN * 64 + 255) / 256);

    if (multisplit) {
        mcount<<<nBlk, blk, 0, stream>>>(dst, cnt, nE, nBkt);
        scanB<<<nBkt, dim3(1024), 0, stream>>>(cnt, offm, tsum, nBlk, nBkt);
        scanT<<<1, dim3(512), 0, stream>>>(tsum, bktbase, row_off, nBkt, nN);
        mscatter<<<nBlk, dim3(512), 0, stream>>>(src, dst, ew, ec, cnt, offm,
                                                 bktbase, epackA, nE, nBlk, nBkt);
        reorder2<<<(nN + 127) / 128, blk, 0, stream>>>(epackA, bktbase,
                                                       row_off, epack, nN);
    } else {
        hipMemsetAsync(counts, 0, (size_t)nN * 4, stream);
        hist_dst<<<edge_blocks, blk, 0, stream>>>(dst, counts, nE);
        scan_partial<<<NB_scan, blk, 0, stream>>>(counts, tsum, nN);
        scan_base<<<1, dim3(512), 0, stream>>>(tsum, bktbase, NB_scan, row_off, nN);
        scan_final<<<NB_scan, blk, 0, stream>>>(counts, bktbase, row_off, cursor, nN);
        fill_csr<<<edge_blocks, blk, 0, stream>>>(src, dst, ew, ec, cursor, epack, nE);
    }

    // ---- weight/input prep (bf16)
    cast_f32_bf16x4<<<(nN * 128 / 4 + 255) / 256, blk, 0, stream>>>(x, xb, nN * 128 / 4);
    conv_w1<<<(9 * 64 * 128 + 255) / 256, blk, 0, stream>>>(W1_rel, W1_root, w1t);
    conv_w2<<<(9 * 48 * 64 + 255) / 256, blk, 0, stream>>>(W2_rel, W2_root, w2t);

    // ---- Layer 1 (gather fuses relu + bf16 cast -> y1b)
    gemm1_mfma<<<dim3(gemm_blocks, 9), blk, 0, stream>>>(xb, w1t, h, agg1, b1, nN);
    gather_relu_d64<<<wave_blocks, blk, 0, stream>>>(h, row_off, epack, agg1, y1b, nN);

    // ---- Layer 2 (gather fuses log_softmax epilogue -> d_out)
    gemm2_mfma<<<dim3(gemm_blocks, 9), blk, 0, stream>>>(y1b, w2t, h, agg2, b2, nN);
    gather_lsm_d40<<<wave_blocks, blk, 0, stream>>>(h, row_off, epack, agg2,
                                                    (float*)d_out, nN);
}

// Round 9
// 383.543 us; speedup vs baseline: 3.2366x; 1.0085x over previous
//
#include <hip/hip_runtime.h>
#include <hip/hip_bf16.h>
#include <cmath>

// WRGCN: 2-layer weighted relational GCN.
// N=100000, E=3200000, R=8, F_IN=128, DIMS=64, C=40.
// Lessons encoded:
//  - scattered partial-line stores/atomics cost a full 64B line each
//    (r4/r5/r6) -> all edge-rate memory ops LDS-staged, flushed linearly.
//  - never funnel E atomics into few cursors (r4: 782 cursors -> 749us).
//  - CSR build has zero global atomics (r7): multisplit counts + scans.
//  - gathers: paired-edge dword loads (r8) + deep MLP unroll (r9: 8
//    outstanding loads/lane d64, 4/lane d40) to drive the L2-miss path.
//  - relu-cast and log_softmax fused into gather epilogues (r8).

#define RELS 8
#define CH 4096       // edges per multisplit chunk
#define ST2CAP 6144   // stage-2 LDS staging capacity (mean 4096)

typedef __attribute__((ext_vector_type(8))) short bf16x8;
typedef __attribute__((ext_vector_type(4))) float f32x4;

static __device__ __forceinline__ ushort f2bf(float f) {
    __hip_bfloat16 b = __float2bfloat16(f);
    return *reinterpret_cast<ushort*>(&b);
}

// ---------------------------------------------------------------------------
// Casts / weight prep
// ---------------------------------------------------------------------------
__global__ __launch_bounds__(256) void cast_f32_bf16x4(
    const float* __restrict__ in, ushort* __restrict__ out, int n4)
{
    int i = blockIdx.x * 256 + threadIdx.x;
    if (i >= n4) return;
    float4 v = ((const float4*)in)[i];
    ushort4 o;
    o.x = f2bf(v.x); o.y = f2bf(v.y); o.z = f2bf(v.z); o.w = f2bf(v.w);
    ((ushort4*)out)[i] = o;
}

// w1t[r][c][k]: r in [0,9): r<8 from W1_rel [R][128][64]; r==8 from W1_root.
__global__ __launch_bounds__(256) void conv_w1(
    const float* __restrict__ Wrel, const float* __restrict__ Wroot,
    ushort* __restrict__ wt)
{
    int i = blockIdx.x * 256 + threadIdx.x;
    if (i >= 9 * 64 * 128) return;
    int r = i >> 13, c = (i >> 7) & 63, k = i & 127;
    float v = (r < 8) ? Wrel[((size_t)r * 128 + k) * 64 + c]
                      : Wroot[(size_t)k * 64 + c];
    wt[i] = f2bf(v);
}

// w2t[r][c][k]: r in [0,9), c in [0,48) (pad 40..47 = 0), k in [0,64).
__global__ __launch_bounds__(256) void conv_w2(
    const float* __restrict__ Wrel, const float* __restrict__ Wroot,
    ushort* __restrict__ wt)
{
    int i = blockIdx.x * 256 + threadIdx.x;
    if (i >= 9 * 48 * 64) return;
    int r = i / (48 * 64), rem = i - r * (48 * 64);
    int c = rem >> 6, k = rem & 63;
    float v = 0.f;
    if (c < 40)
        v = (r < 8) ? Wrel[((size_t)r * 64 + k) * 40 + c]
                    : Wroot[(size_t)k * 40 + c];
    wt[i] = f2bf(v);
}

// ---------------------------------------------------------------------------
// Layer-1 GEMMs (MFMA bf16), blockIdx.y in [0,9):
//   y<8 : h[y][n][0:64] = xb[n][0:128] @ W1_rel[y]      (bf16 out)
//   y==8: agg1[n][0:64] = xb[n][0:128] @ W1_root + b1   (f32 out)
// ---------------------------------------------------------------------------
__global__ __launch_bounds__(256) void gemm1_mfma(
    const ushort* __restrict__ xb, const ushort* __restrict__ w1t,
    ushort* __restrict__ hout, float* __restrict__ agg1,
    const float* __restrict__ b1, int nN)
{
    __shared__ ushort xs[64 * 128];
    __shared__ ushort wt[64 * 128];
    const int y    = blockIdx.y;
    const int tid  = threadIdx.x;
    const int n0   = blockIdx.x * 64;
    const int nmax = nN - n0;
    const bool isroot = (y == 8);
    ushort* out = hout + (size_t)y * nN * 64;
    const ushort* wsrc = w1t + (size_t)y * 64 * 128;

    for (int i = tid; i < 1024; i += 256) {
        int row = i >> 4, ch = i & 15;
        uint4 v = make_uint4(0u, 0u, 0u, 0u);
        if (row < nmax)
            v = *(const uint4*)(xb + (size_t)(n0 + row) * 128 + ch * 8);
        int off = (row * 256 + ch * 16) ^ ((row & 7) << 4);
        *(uint4*)((char*)xs + off) = v;
    }
    for (int i = tid; i < 1024; i += 256) {
        int row = i >> 4, ch = i & 15;
        uint4 v = *(const uint4*)(wsrc + (size_t)row * 128 + ch * 8);
        int off = (row * 256 + ch * 16) ^ ((row & 7) << 4);
        *(uint4*)((char*)wt + off) = v;
    }
    __syncthreads();

    const int wv   = tid >> 6;
    const int lane = tid & 63;
    const int lr   = wv * 16 + (lane & 15);
    const int kgb  = (lane >> 4) * 8;

    f32x4 acc[4] = {{0.f,0.f,0.f,0.f},{0.f,0.f,0.f,0.f},
                    {0.f,0.f,0.f,0.f},{0.f,0.f,0.f,0.f}};

    #pragma unroll
    for (int ks = 0; ks < 4; ++ks) {
        int kb = (ks * 32 + kgb) * 2;
        int aoff = (lr * 256 + kb) ^ ((lr & 7) << 4);
        bf16x8 a = *(const bf16x8*)((const char*)xs + aoff);
        #pragma unroll
        for (int ct = 0; ct < 4; ++ct) {
            int col = ct * 16 + (lane & 15);
            int boff = (col * 256 + kb) ^ ((col & 7) << 4);
            bf16x8 b = *(const bf16x8*)((const char*)wt + boff);
            acc[ct] = __builtin_amdgcn_mfma_f32_16x16x32_bf16(a, b, acc[ct], 0, 0, 0);
        }
    }

    #pragma unroll
    for (int ct = 0; ct < 4; ++ct) {
        int col = ct * 16 + (lane & 15);
        #pragma unroll
        for (int reg = 0; reg < 4; ++reg) {
            int row = wv * 16 + (lane >> 4) * 4 + reg;
            if (row < nmax) {
                if (isroot)
                    agg1[(size_t)(n0 + row) * 64 + col] = acc[ct][reg] + b1[col];
                else
                    out[(size_t)(n0 + row) * 64 + col] = f2bf(acc[ct][reg]);
            }
        }
    }
}

// ---------------------------------------------------------------------------
// Layer-2 GEMMs (MFMA bf16), blockIdx.y in [0,9):
//   y<8 : h2[y][n][0:40] = y1b[n][0:64] @ W2_rel[y]     (bf16 out)
//   y==8: agg2[n][0:40] = y1b[n][0:64] @ W2_root + b2   (f32 out)
// ---------------------------------------------------------------------------
__global__ __launch_bounds__(256) void gemm2_mfma(
    const ushort* __restrict__ y1b, const ushort* __restrict__ w2t,
    ushort* __restrict__ hout, float* __restrict__ agg2,
    const float* __restrict__ b2, int nN)
{
    __shared__ ushort ys[64 * 64];
    __shared__ ushort wt[48 * 64];
    const int y    = blockIdx.y;
    const int tid  = threadIdx.x;
    const int n0   = blockIdx.x * 64;
    const int nmax = nN - n0;
    const bool isroot = (y == 8);
    ushort* out = hout + (size_t)y * nN * 40;
    const ushort* wsrc = w2t + (size_t)y * 48 * 64;

    for (int i = tid; i < 512; i += 256) {
        int row = i >> 3, ch = i & 7;
        uint4 v = make_uint4(0u, 0u, 0u, 0u);
        if (row < nmax)
            v = *(const uint4*)(y1b + (size_t)(n0 + row) * 64 + ch * 8);
        int off = (row * 128 + ch * 16) ^ ((row & 7) << 4);
        *(uint4*)((char*)ys + off) = v;
    }
    for (int i = tid; i < 384; i += 256) {
        int row = i >> 3, ch = i & 7;
        uint4 v = *(const uint4*)(wsrc + (size_t)row * 64 + ch * 8);
        int off = (row * 128 + ch * 16) ^ ((row & 7) << 4);
        *(uint4*)((char*)wt + off) = v;
    }
    __syncthreads();

    const int wv   = tid >> 6;
    const int lane = tid & 63;
    const int lr   = wv * 16 + (lane & 15);
    const int kgb  = (lane >> 4) * 8;

    f32x4 acc[3] = {{0.f,0.f,0.f,0.f},{0.f,0.f,0.f,0.f},{0.f,0.f,0.f,0.f}};

    #pragma unroll
    for (int ks = 0; ks < 2; ++ks) {
        int kb = (ks * 32 + kgb) * 2;
        int aoff = (lr * 128 + kb) ^ ((lr & 7) << 4);
        bf16x8 a = *(const bf16x8*)((const char*)ys + aoff);
        #pragma unroll
        for (int ct = 0; ct < 3; ++ct) {
            int col = ct * 16 + (lane & 15);
            int boff = (col * 128 + kb) ^ ((col & 7) << 4);
            bf16x8 b = *(const bf16x8*)((const char*)wt + boff);
            acc[ct] = __builtin_amdgcn_mfma_f32_16x16x32_bf16(a, b, acc[ct], 0, 0, 0);
        }
    }

    #pragma unroll
    for (int ct = 0; ct < 3; ++ct) {
        int col = ct * 16 + (lane & 15);
        if (col < 40) {
            #pragma unroll
            for (int reg = 0; reg < 4; ++reg) {
                int row = wv * 16 + (lane >> 4) * 4 + reg;
                if (row < nmax) {
                    if (isroot)
                        agg2[(size_t)(n0 + row) * 40 + col] = acc[ct][reg] + b2[col];
                    else
                        out[(size_t)(n0 + row) * 40 + col] = f2bf(acc[ct][reg]);
                }
            }
        }
    }
}

// ---------------------------------------------------------------------------
// CSR build: two-stage multisplit, zero global atomics.
// payload pk: bits 0..19 src, 20..22 color, 23..30 dst&255
// ---------------------------------------------------------------------------
__global__ __launch_bounds__(256) void mcount(
    const int* __restrict__ dst, int* __restrict__ cnt, int nE, int nBkt)
{
    __shared__ int hist[512];
    const int blk = blockIdx.x;
    const int t = threadIdx.x;
    for (int i = t; i < nBkt; i += 256) hist[i] = 0;
    __syncthreads();
    const int e0 = blk * CH;
    const int eend = min(e0 + CH, nE);
    for (int e = e0 + t; e < eend; e += 256)
        atomicAdd(&hist[dst[e] >> 8], 1);
    __syncthreads();
    for (int i = t; i < nBkt; i += 256)
        cnt[(size_t)blk * nBkt + i] = hist[i];
}

__global__ __launch_bounds__(1024) void scanB(
    const int* __restrict__ cnt, int* __restrict__ offm_rel,
    int* __restrict__ tsum, int nBlk, int nBkt)
{
    __shared__ int s[1024];
    const int bkt = blockIdx.x;
    const int t = threadIdx.x;
    int v = (t < nBlk) ? cnt[(size_t)t * nBkt + bkt] : 0;
    s[t] = v; __syncthreads();
    for (int o = 1; o < 1024; o <<= 1) {
        int u = (t >= o) ? s[t - o] : 0;
        __syncthreads(); s[t] += u; __syncthreads();
    }
    if (t < nBlk) offm_rel[(size_t)bkt * nBlk + t] = s[t] - v;
    if (t == nBlk - 1) tsum[bkt] = s[t];
}

__global__ __launch_bounds__(512) void scanT(
    const int* __restrict__ tsum, int* __restrict__ bktbase,
    int* __restrict__ row_off, int nBkt, int nN)
{
    __shared__ int s[512];
    const int t = threadIdx.x;
    int v = (t < nBkt) ? tsum[t] : 0;
    s[t] = v; __syncthreads();
    for (int o = 1; o < 512; o <<= 1) {
        int u = (t >= o) ? s[t - o] : 0;
        __syncthreads(); s[t] += u; __syncthreads();
    }
    if (t < nBkt) bktbase[t] = s[t] - v;
    if (t == nBkt - 1) { bktbase[nBkt] = s[t]; row_off[nN] = s[t]; }
}

__global__ __launch_bounds__(512) void mscatter(
    const int* __restrict__ src, const int* __restrict__ dst,
    const float* __restrict__ ew, const int* __restrict__ ec,
    const int* __restrict__ cnt, const int* __restrict__ offm_rel,
    const int* __restrict__ bktbase,
    uint2* __restrict__ epackA, int nE, int nBlk, int nBkt)
{
    __shared__ uint2 stag[CH];
    __shared__ int lbase[512];
    __shared__ int lcur[512];
    __shared__ int goff[512];
    const int blk = blockIdx.x;
    const int t = threadIdx.x;

    int v = (t < nBkt) ? cnt[(size_t)blk * nBkt + t] : 0;
    lbase[t] = v; __syncthreads();
    for (int o = 1; o < 512; o <<= 1) {
        int u = (t >= o) ? lbase[t - o] : 0;
        __syncthreads(); lbase[t] += u; __syncthreads();
    }
    int excl = lbase[t] - v;
    __syncthreads();
    lbase[t] = excl;
    lcur[t] = excl;
    goff[t] = (t < nBkt) ? bktbase[t] + offm_rel[(size_t)t * nBlk + blk] : 0;
    __syncthreads();

    const int e0 = blk * CH;
    const int eend = min(e0 + CH, nE);
    const int ntot = eend - e0;
    for (int e = e0 + t; e < eend; e += 512) {
        int d = dst[e];
        int bkt = d >> 8;
        unsigned int pk = (unsigned int)src[e] | ((unsigned int)ec[e] << 20)
                        | ((unsigned int)(d & 255) << 23);
        int r = atomicAdd(&lcur[bkt], 1);
        stag[r] = make_uint2(pk, __float_as_uint(ew[e]));
    }
    __syncthreads();
    for (int s2 = t; s2 < ntot; s2 += 512) {
        int lo = 0, hi = nBkt - 1;
        while (lo < hi) {
            int mid = (lo + hi + 1) >> 1;
            if (lbase[mid] <= s2) lo = mid; else hi = mid - 1;
        }
        epackA[goff[lo] + (s2 - lbase[lo])] = stag[s2];
    }
}

// stage 2: one block per 128-node half of a 256-node bucket.
__global__ __launch_bounds__(256) void reorder2(
    const uint2* __restrict__ epackA, const int* __restrict__ bktbase,
    int* __restrict__ row_off, uint2* __restrict__ epack, int nN)
{
    __shared__ uint2 stag[ST2CAP];
    __shared__ int hist[256];
    __shared__ int s[256];
    __shared__ int lcur[128];
    const int b    = blockIdx.x;
    const int n0   = b << 7;
    const int pb   = b >> 1;
    const int half = b & 1;
    const int p0 = bktbase[pb];
    const int p1 = bktbase[pb + 1];
    const int t = threadIdx.x;

    hist[t] = 0;
    __syncthreads();
    const unsigned int* ax = (const unsigned int*)epackA;
    for (int e = p0 + t; e < p1; e += 256)
        atomicAdd(&hist[(ax[2 * (size_t)e] >> 23) & 255], 1);
    __syncthreads();
    int v = hist[t];
    s[t] = v; __syncthreads();
    for (int o = 1; o < 256; o <<= 1) {
        int u = (t >= o) ? s[t - o] : 0;
        __syncthreads(); s[t] += u; __syncthreads();
    }
    hist[t] = s[t] - v;
    __syncthreads();

    const int hb0 = hist[half << 7];
    const int hb1 = (half == 0) ? hist[128] : (p1 - p0);
    const int ne  = hb1 - hb0;
    const int s0  = p0 + hb0;

    if (t < 128) {
        int idx = n0 + t;
        if (idx < nN) row_off[idx] = p0 + hist[(half << 7) + t];
        lcur[t] = hist[(half << 7) + t] - hb0;
    }
    __syncthreads();

    if (ne <= ST2CAP) {
        for (int e = p0 + t; e < p1; e += 256) {
            uint2 pw = epackA[e];
            int dl = (pw.x >> 23) & 255;
            if ((dl >> 7) == half) {
                int r = atomicAdd(&lcur[dl & 127], 1);
                stag[r] = pw;
            }
        }
        __syncthreads();
        for (int s2 = t; s2 < ne; s2 += 256)
            epack[s0 + s2] = stag[s2];
    } else {
        if (t < 128) {
            int my = (half << 7) | t;
            int wpos = p0 + hist[my];
            for (int e = p0; e < p1; ++e) {
                uint2 pw = epackA[e];
                if ((int)((pw.x >> 23) & 255) == my) epack[wpos++] = pw;
            }
        }
    }
}

// ---------------------------------------------------------------------------
// Fallback CSR build (non-multisplit shapes)
// ---------------------------------------------------------------------------
__global__ __launch_bounds__(256) void hist_dst(
    const int* __restrict__ dst, int* __restrict__ counts, int nE)
{
    int e = blockIdx.x * 256 + threadIdx.x;
    if (e < nE) atomicAdd(&counts[dst[e]], 1);
}

__global__ __launch_bounds__(256) void scan_partial(
    const int* __restrict__ counts, int* __restrict__ bsum, int nN)
{
    __shared__ int s[256];
    int t = threadIdx.x;
    int i = blockIdx.x * 256 + t;
    int v = (i < nN) ? counts[i] : 0;
    s[t] = v; __syncthreads();
    for (int o = 1; o < 256; o <<= 1) {
        int u = (t >= o) ? s[t - o] : 0;
        __syncthreads(); s[t] += u; __syncthreads();
    }
    if (t == 255) bsum[blockIdx.x] = s[255];
}

__global__ __launch_bounds__(512) void scan_base(
    const int* __restrict__ bsum, int* __restrict__ bbase, int nb,
    int* __restrict__ row_off, int nN)
{
    __shared__ int s[512];
    int t = threadIdx.x;
    int v = (t < nb) ? bsum[t] : 0;
    s[t] = v; __syncthreads();
    for (int o = 1; o < 512; o <<= 1) {
        int u = (t >= o) ? s[t - o] : 0;
        __syncthreads(); s[t] += u; __syncthreads();
    }
    if (t < nb) bbase[t] = s[t] - v;
    if (t == nb - 1) row_off[nN] = s[t];
}

__global__ __launch_bounds__(256) void scan_final(
    const int* __restrict__ counts, const int* __restrict__ bbase,
    int* __restrict__ row_off, int* __restrict__ cursor, int nN)
{
    __shared__ int s[256];
    int t = threadIdx.x;
    int i = blockIdx.x * 256 + t;
    int v = (i < nN) ? counts[i] : 0;
    s[t] = v; __syncthreads();
    for (int o = 1; o < 256; o <<= 1) {
        int u = (t >= o) ? s[t - o] : 0;
        __syncthreads(); s[t] += u; __syncthreads();
    }
    if (i < nN) {
        int off = bbase[blockIdx.x] + s[t] - v;
        row_off[i] = off;
        cursor[i]  = off;
    }
}

__global__ __launch_bounds__(256) void fill_csr(
    const int* __restrict__ src, const int* __restrict__ dst,
    const float* __restrict__ ew, const int* __restrict__ ec,
    int* __restrict__ cursor, uint2* __restrict__ epack, int nE)
{
    int e = blockIdx.x * 256 + threadIdx.x;
    if (e >= nE) return;
    int p = atomicAdd(&cursor[dst[e]], 1);
    epack[p] = make_uint2((unsigned int)src[e] | ((unsigned int)ec[e] << 20),
                          __float_as_uint(ew[e]));
}

// ---------------------------------------------------------------------------
// Gather layer 1 + fused relu/bf16 cast. One wave per dst node.
// 2 edges in flight laterally (half=lane>>5), 8 loads deep per lane.
// ---------------------------------------------------------------------------
__global__ __launch_bounds__(256) void gather_relu_d64(
    const ushort* __restrict__ h, const int* __restrict__ row_off,
    const uint2* __restrict__ epack, const float* __restrict__ agg1,
    ushort* __restrict__ y1b, int nN)
{
    int w    = (blockIdx.x * 256 + threadIdx.x) >> 6;
    int lane = threadIdx.x & 63;
    if (w >= nN) return;
    const int half = lane >> 5;
    const int hl   = lane & 31;
    const unsigned int un = (unsigned int)nN;
    int s0 = row_off[w], s1 = row_off[w + 1];

    float a0 = 0.f, a1 = 0.f;
    if (half == 0) {
        float2 iv = *(const float2*)(agg1 + (size_t)w * 64 + 2 * hl);
        a0 = iv.x; a1 = iv.y;
    }

    for (int base = s0; base < s1; base += 64) {
        int m = min(64, s1 - base);
        unsigned int pk = 0; float wv = 0.f;
        if (lane < m) {
            uint2 pw = epack[base + lane];
            pk = pw.x; wv = __uint_as_float(pw.y);
        }
        int j = 0;
        for (; j + 16 <= m; j += 16) {
            unsigned int p_[8]; float q_[8]; unsigned int v_[8];
            #pragma unroll
            for (int u = 0; u < 8; ++u) {
                p_[u] = __shfl(pk, j + 2 * u + half, 64);
                q_[u] = __shfl(wv, j + 2 * u + half, 64);
            }
            #pragma unroll
            for (int u = 0; u < 8; ++u)
                v_[u] = *(const unsigned int*)(h + ((((p_[u] >> 20) & 7) * un + (p_[u] & 0xFFFFFu)) * 64u + 2u * hl));
            #pragma unroll
            for (int u = 0; u < 8; ++u) {
                a0 = fmaf(q_[u], __uint_as_float(v_[u] << 16), a0);
                a1 = fmaf(q_[u], __uint_as_float(v_[u] & 0xFFFF0000u), a1);
            }
        }
        for (; j + 8 <= m; j += 8) {
            unsigned int p_[4]; float q_[4]; unsigned int v_[4];
            #pragma unroll
            for (int u = 0; u < 4; ++u) {
                p_[u] = __shfl(pk, j + 2 * u + half, 64);
                q_[u] = __shfl(wv, j + 2 * u + half, 64);
            }
            #pragma unroll
            for (int u = 0; u < 4; ++u)
                v_[u] = *(const unsigned int*)(h + ((((p_[u] >> 20) & 7) * un + (p_[u] & 0xFFFFFu)) * 64u + 2u * hl));
            #pragma unroll
            for (int u = 0; u < 4; ++u) {
                a0 = fmaf(q_[u], __uint_as_float(v_[u] << 16), a0);
                a1 = fmaf(q_[u], __uint_as_float(v_[u] & 0xFFFF0000u), a1);
            }
        }
        for (; j + 2 <= m; j += 2) {
            unsigned int p = __shfl(pk, j + half, 64);
            float q = __shfl(wv, j + half, 64);
            unsigned int v = *(const unsigned int*)(h + ((((p >> 20) & 7) * un + (p & 0xFFFFFu)) * 64u + 2u * hl));
            a0 = fmaf(q, __uint_as_float(v << 16), a0);
            a1 = fmaf(q, __uint_as_float(v & 0xFFFF0000u), a1);
        }
        if (j < m) {   // odd tail: half 0 only
            unsigned int p = __shfl(pk, j, 64);
            float q = __shfl(wv, j, 64);
            if (half == 0) {
                unsigned int v = *(const unsigned int*)(h + ((((p >> 20) & 7) * un + (p & 0xFFFFFu)) * 64u + 2u * hl));
                a0 = fmaf(q, __uint_as_float(v << 16), a0);
                a1 = fmaf(q, __uint_as_float(v & 0xFFFF0000u), a1);
            }
        }
    }
    a0 += __shfl_xor(a0, 32, 64);
    a1 += __shfl_xor(a1, 32, 64);
    if (half == 0) {
        unsigned int b0 = f2bf(fmaxf(a0, 0.f));
        unsigned int b1 = f2bf(fmaxf(a1, 0.f));
        *(unsigned int*)(y1b + (size_t)w * 64 + 2 * hl) = b0 | (b1 << 16);
    }
}

// ---------------------------------------------------------------------------
// Gather layer 2 + fused log_softmax epilogue. One wave per dst node.
// 3 edges laterally (g=lane/20), 4 loads deep per lane.
// ---------------------------------------------------------------------------
__global__ __launch_bounds__(256) void gather_lsm_d40(
    const ushort* __restrict__ h, const int* __restrict__ row_off,
    const uint2* __restrict__ epack, const float* __restrict__ agg2,
    float* __restrict__ out, int nN)
{
    int w    = (blockIdx.x * 256 + threadIdx.x) >> 6;
    int lane = threadIdx.x & 63;
    if (w >= nN) return;
    const int g  = lane / 20;          // 0..2 active, 3 idle
    const int hl = lane - g * 20;
    const unsigned int un = (unsigned int)nN;
    int s0 = row_off[w], s1 = row_off[w + 1];

    float a0 = 0.f, a1 = 0.f;
    if (g == 0) {
        float2 iv = *(const float2*)(agg2 + (size_t)w * 40 + 2 * hl);
        a0 = iv.x; a1 = iv.y;
    }

    for (int base = s0; base < s1; base += 64) {
        int m = min(64, s1 - base);
        unsigned int pk = 0; float wv = 0.f;
        if (lane < m) {
            uint2 pw = epack[base + lane];
            pk = pw.x; wv = __uint_as_float(pw.y);
        }
        int j = 0;
        for (; j + 12 <= m; j += 12) {
            unsigned int p_[4]; float q_[4]; unsigned int v_[4];
            #pragma unroll
            for (int u = 0; u < 4; ++u) {
                p_[u] = __shfl(pk, j + 3 * u + g, 64);
                q_[u] = __shfl(wv, j + 3 * u + g, 64);
            }
            #pragma unroll
            for (int u = 0; u < 4; ++u)
                v_[u] = *(const unsigned int*)(h + ((((p_[u] >> 20) & 7) * un + (p_[u] & 0xFFFFFu)) * 40u + 2u * hl));
            #pragma unroll
            for (int u = 0; u < 4; ++u) {
                a0 = fmaf(q_[u], __uint_as_float(v_[u] << 16), a0);
                a1 = fmaf(q_[u], __uint_as_float(v_[u] & 0xFFFF0000u), a1);
            }
        }
        for (; j + 6 <= m; j += 6) {
            unsigned int pA = __shfl(pk, j + g, 64);
            unsigned int pB = __shfl(pk, j + 3 + g, 64);
            float qA = __shfl(wv, j + g, 64);
            float qB = __shfl(wv, j + 3 + g, 64);
            unsigned int vA = *(const unsigned int*)(h + ((((pA >> 20) & 7) * un + (pA & 0xFFFFFu)) * 40u + 2u * hl));
            unsigned int vB = *(const unsigned int*)(h + ((((pB >> 20) & 7) * un + (pB & 0xFFFFFu)) * 40u + 2u * hl));
            a0 = fmaf(qA, __uint_as_float(vA << 16), a0);
            a1 = fmaf(qA, __uint_as_float(vA & 0xFFFF0000u), a1);
            a0 = fmaf(qB, __uint_as_float(vB << 16), a0);
            a1 = fmaf(qB, __uint_as_float(vB & 0xFFFF0000u), a1);
        }
        for (; j + 3 <= m; j += 3) {
            unsigned int p = __shfl(pk, j + g, 64);
            float q = __shfl(wv, j + g, 64);
            unsigned int v = *(const unsigned int*)(h + ((((p >> 20) & 7) * un + (p & 0xFFFFFu)) * 40u + 2u * hl));
            a0 = fmaf(q, __uint_as_float(v << 16), a0);
            a1 = fmaf(q, __uint_as_float(v & 0xFFFF0000u), a1);
        }
        for (; j < m; ++j) {   // tail 1-2 edges: group 0 only
            unsigned int p = __shfl(pk, j, 64);
            float q = __shfl(wv, j, 64);
            if (g == 0) {
                unsigned int v = *(const unsigned int*)(h + ((((p >> 20) & 7) * un + (p & 0xFFFFFu)) * 40u + 2u * hl));
                a0 = fmaf(q, __uint_as_float(v << 16), a0);
                a1 = fmaf(q, __uint_as_float(v & 0xFFFF0000u), a1);
            }
        }
    }
    // combine the 3 edge-groups (values live at lanes hl, hl+20, hl+40)
    float b0 = __shfl(a0, hl + 20, 64), c0 = __shfl(a0, hl + 40, 64);
    float b1 = __shfl(a1, hl + 20, 64), c1 = __shfl(a1, hl + 40, 64);
    a0 += b0 + c0;
    a1 += b1 + c1;

    // log_softmax over the 40 dims (pairs in lanes 0..19)
    float mx = (g == 0) ? fmaxf(a0, a1) : -INFINITY;
    #pragma unroll
    for (int o = 32; o > 0; o >>= 1) mx = fmaxf(mx, __shfl_xor(mx, o, 64));
    float ex = (g == 0) ? (expf(a0 - mx) + expf(a1 - mx)) : 0.f;
    #pragma unroll
    for (int o = 32; o > 0; o >>= 1) ex += __shfl_xor(ex, o, 64);
    float lse = logf(ex) + mx;

    if (g == 0) {
        *(float2*)(out + (size_t)w * 40 + 2 * hl) = make_float2(a0 - lse, a1 - lse);
        *(float2*)(out + (size_t)nN * 40 + (size_t)w * 40 + 2 * hl) = make_float2(a0, a1);
    }
}

// ---------------------------------------------------------------------------
extern "C" void kernel_launch(void* const* d_in, const int* in_sizes, int n_in,
                              void* d_out, int out_size, void* d_ws, size_t ws_size,
                              hipStream_t stream)
{
    const float* x       = (const float*)d_in[0];
    const int*   eidx    = (const int*)  d_in[1];
    const float* ew      = (const float*)d_in[2];
    const int*   ec      = (const int*)  d_in[3];
    const float* W1_rel  = (const float*)d_in[4];
    const float* W1_root = (const float*)d_in[5];
    const float* b1      = (const float*)d_in[6];
    const float* W2_rel  = (const float*)d_in[7];
    const float* W2_root = (const float*)d_in[8];
    const float* b2      = (const float*)d_in[9];

    const int nN = in_sizes[0] / 128;   // 100000
    const int nE = in_sizes[2];         // 3200000
    const int* src = eidx;
    const int* dst = eidx + nE;

    const int nBkt = (nN + 255) >> 8;          // 391 stage-1 buckets
    const int nBlk = (nE + CH - 1) / CH;       // 782 multisplit chunks

    char* w8 = (char*)d_ws;
    size_t off = 0;
    auto alloc = [&](size_t bytes) {
        void* p = w8 + off;
        off += (bytes + 255) & ~(size_t)255;
        return p;
    };
    ushort* h      = (ushort*)alloc((size_t)RELS * nN * 64 * 2);
    ushort* xb     = (ushort*)alloc((size_t)nN * 128 * 2);
    float*  agg1   = (float*) alloc((size_t)nN * 64 * 4);
    float*  agg2   = (float*) alloc((size_t)nN * 40 * 4);
    int*    counts = (int*)   alloc((size_t)nN * 4);
    int*    row_off= (int*)   alloc(((size_t)nN + 1) * 4);
    int*    cursor = (int*)   alloc((size_t)nN * 4);
    int*    tsum   = (int*)   alloc(4096);
    int*    bktbase= (int*)   alloc(4096);
    uint2*  epack  = (uint2*) alloc((size_t)nE * 8);
    ushort* w1t    = (ushort*)alloc((size_t)9 * 64 * 128 * 2);
    ushort* w2t    = (ushort*)alloc((size_t)9 * 48 * 64 * 2);
    int*    cnt    = (int*)   alloc((size_t)nBlk * nBkt * 4);
    int*    offm   = (int*)   alloc((size_t)nBkt * nBlk * 4);
    uint2*  epackA = (uint2*) alloc((size_t)nE * 8);
    const bool multisplit = (off <= ws_size) && (nBlk <= 1024) && (nBkt <= 512)
                            && (nN < (1 << 20));
    ushort* y1b = xb;   // x bf16 dead after layer-1 GEMMs

    const dim3 blk(256);
    const int NB_scan     = (nN + 255) / 256;
    const int gemm_blocks = (nN + 63) / 64;
    const int edge_blocks = (nE + 255) / 256;
    const int wave_blocks = (int)(((size_t)nN * 64 + 255) / 256);

    if (multisplit) {
        mcount<<<nBlk, blk, 0, stream>>>(dst, cnt, nE, nBkt);
        scanB<<<nBkt, dim3(1024), 0, stream>>>(cnt, offm, tsum, nBlk, nBkt);
        scanT<<<1, dim3(512), 0, stream>>>(tsum, bktbase, row_off, nBkt, nN);
        mscatter<<<nBlk, dim3(512), 0, stream>>>(src, dst, ew, ec, cnt, offm,
                                                 bktbase, epackA, nE, nBlk, nBkt);
        reorder2<<<(nN + 127) / 128, blk, 0, stream>>>(epackA, bktbase,
                                                       row_off, epack, nN);
    } else {
        hipMemsetAsync(counts, 0, (size_t)nN * 4, stream);
        hist_dst<<<edge_blocks, blk, 0, stream>>>(dst, counts, nE);
        scan_partial<<<NB_scan, blk, 0, stream>>>(counts, tsum, nN);
        scan_base<<<1, dim3(512), 0, stream>>>(tsum, bktbase, NB_scan, row_off, nN);
        scan_final<<<NB_scan, blk, 0, stream>>>(counts, bktbase, row_off, cursor, nN);
        fill_csr<<<edge_blocks, blk, 0, stream>>>(src, dst, ew, ec, cursor, epack, nE);
    }

    // ---- weight/input prep (bf16)
    cast_f32_bf16x4<<<(nN * 128 / 4 + 255) / 256, blk, 0, stream>>>(x, xb, nN * 128 / 4);
    conv_w1<<<(9 * 64 * 128 + 255) / 256, blk, 0, stream>>>(W1_rel, W1_root, w1t);
    conv_w2<<<(9 * 48 * 64 + 255) / 256, blk, 0, stream>>>(W2_rel, W2_root, w2t);

    // ---- Layer 1 (gather fuses relu + bf16 cast -> y1b)
    gemm1_mfma<<<dim3(gemm_blocks, 9), blk, 0, stream>>>(xb, w1t, h, agg1, b1, nN);
    gather_relu_d64<<<wave_blocks, blk, 0, stream>>>(h, row_off, epack, agg1, y1b, nN);

    // ---- Layer 2 (gather fuses log_softmax epilogue -> d_out)
    gemm2_mfma<<<dim3(gemm_blocks, 9), blk, 0, stream>>>(y1b, w2t, h, agg2, b2, nN);
    gather_lsm_d40<<<wave_blocks, blk, 0, stream>>>(h, row_off, epack, agg2,
                                                    (float*)d_out, nN);
}